// Round 21
// baseline (284.396 us; speedup 1.0000x reference)
//
#include <hip/hip_runtime.h>

#define HH 256       // hidden size
#define NB 64        // batch (segments)
#define ROWS 64      // rows per block tile
#define NTOT 262144  // NK == NC
#define THREADS 256  // 4 waves

typedef _Float16 half8 __attribute__((ext_vector_type(8)));
typedef _Float16 half4 __attribute__((ext_vector_type(4)));
typedef float f32x4 __attribute__((ext_vector_type(4)));

typedef __attribute__((address_space(1))) const void gas_t;
typedef __attribute__((address_space(3))) void las_t;

// act LDS tile: [row][k] fp16, 64 rows x 256 k = 32KB, row stride 512B.
__device__ __forceinline__ uint32_t swz(uint32_t r, uint32_t k) {
  return (((r << 9) + (k << 1)) ^ ((r & 7) << 4)) ^ ((r & 8) << 3);
}

// Stage one wave-private 4KB A-slab (64 j x 32 k): 4 DMA calls x 1KB.
__device__ __forceinline__ void stage_slab(const char* __restrict__ g, char* l,
                                           int lane)
{
  const char* gp = g + lane * 16;
#pragma unroll
  for (int c = 0; c < 4; ++c)
    __builtin_amdgcn_global_load_lds((gas_t*)(gp + c * 1024), (las_t*)(l + c * 1024),
                                     16, 0, 0);
}

// ---------------------------------------------------------------------------
// R17 heavy layer (best measured): MFMA swapped operands, A from wave-private
// DMA slabs (3-deep, counted vmcnt), both operands double-buffered in regs.
// MODE: 0 relu; 1 plain; 2 multiply seg_mean[seg_g[r]] (branch mixed path)
// ---------------------------------------------------------------------------
template<int MODE>
__device__ __forceinline__ void heavy_layer(char* act, char* wpan,
                                            const char* __restrict__ wt3,
                                            const float* __restrict__ bias,
                                            const float* __restrict__ seg_mean,
                                            const int* __restrict__ seg_g, int tid)
{
  const int wid  = tid >> 6;
  const int lane = tid & 63;
  const int lr   = lane & 15;
  const int lg   = lane >> 4;
  const int j0   = wid << 6;
  char* slab = wpan + wid * 12288;
  const char* wsrc = wt3 + wid * 4096;

  f32x4 acc[4][4];
#pragma unroll
  for (int jf = 0; jf < 4; ++jf)
#pragma unroll
    for (int rf = 0; rf < 4; ++rf)
      acc[jf][rf] = (f32x4){0.f, 0.f, 0.f, 0.f};

  stage_slab(wsrc + 0 * 16384, slab + 0 * 4096, lane);
  stage_slab(wsrc + 1 * 16384, slab + 1 * 4096, lane);
  stage_slab(wsrc + 2 * 16384, slab + 2 * 4096, lane);

  half8 a[2][4], b[2][4];

  asm volatile("s_waitcnt vmcnt(8)" ::: "memory");
  __builtin_amdgcn_sched_barrier(0);
#pragma unroll
  for (int rf = 0; rf < 4; ++rf)
    b[0][rf] = *(const half8*)(act + swz(rf * 16 + lr, 0 * 32 + lg * 8));
#pragma unroll
  for (int jf = 0; jf < 4; ++jf)
    a[0][jf] = *(const half8*)(slab + 0 * 4096 + jf * 1024 + lane * 16);

#pragma unroll
  for (int ks = 0; ks < 8; ++ks) {
    const int p = ks & 1;
    if (ks < 7) {
      if (ks < 6) asm volatile("s_waitcnt vmcnt(4)" ::: "memory");
      else        asm volatile("s_waitcnt vmcnt(0)" ::: "memory");
      __builtin_amdgcn_sched_barrier(0);
#pragma unroll
      for (int rf = 0; rf < 4; ++rf)
        b[p ^ 1][rf] = *(const half8*)(act + swz(rf * 16 + lr, (ks + 1) * 32 + lg * 8));
#pragma unroll
      for (int jf = 0; jf < 4; ++jf)
        a[p ^ 1][jf] = *(const half8*)(slab + ((ks + 1) % 3) * 4096 + jf * 1024 + lane * 16);
    }
    __builtin_amdgcn_sched_barrier(0);
#pragma unroll
    for (int jf = 0; jf < 4; ++jf)
#pragma unroll
      for (int rf = 0; rf < 4; ++rf)
        acc[jf][rf] = __builtin_amdgcn_mfma_f32_16x16x32_f16(a[p][jf], b[p][rf], acc[jf][rf], 0, 0, 0);
    __builtin_amdgcn_sched_barrier(0);
    if (ks < 5)
      stage_slab(wsrc + (ks + 3) * 16384, slab + (ks % 3) * 4096, lane);
  }

  int sseg[4];
  if (MODE == 2) {
#pragma unroll
    for (int rf = 0; rf < 4; ++rf) sseg[rf] = seg_g[rf * 16 + lr];
  }

  __syncthreads();  // all waves done READING act before overwrite

#pragma unroll
  for (int jf = 0; jf < 4; ++jf) {
    f32x4 bj = *(const f32x4*)(bias + j0 + jf * 16 + lg * 4);
#pragma unroll
    for (int rf = 0; rf < 4; ++rf) {
      f32x4 v = acc[jf][rf] + bj;
      if (MODE == 2) {
        f32x4 sm = *(const f32x4*)(seg_mean + sseg[rf] * HH + j0 + jf * 16 + lg * 4);
        v *= sm;
      }
      half4 h;
#pragma unroll
      for (int u = 0; u < 4; ++u) {
        float x = v[u];
        if (MODE == 0) x = fmaxf(x, 0.f);
        h[u] = (_Float16)x;
      }
      *(half4*)(act + swz(rf * 16 + lr, j0 + jf * 16 + lg * 4)) = h;
    }
  }
  __syncthreads();
}

// ---------------------------------------------------------------------------
// Fused C_s layer, L2-streamed (R7-proven loop): h = relu(C_s a + d_s).
// C row-major [j][k] fp16; shared by ~64 blocks -> L2-hot.
// ---------------------------------------------------------------------------
__device__ __forceinline__ void stream_layer(char* act, const _Float16* __restrict__ WT,
                                             const float* __restrict__ dbias, int tid)
{
  const int wid  = tid >> 6;
  const int lane = tid & 63;
  const int lr   = lane & 15;
  const int lg   = lane >> 4;
  const int j0   = wid << 6;

  f32x4 acc[4][4];
#pragma unroll
  for (int jf = 0; jf < 4; ++jf)
#pragma unroll
    for (int rf = 0; rf < 4; ++rf)
      acc[jf][rf] = (f32x4){0.f, 0.f, 0.f, 0.f};

  const _Float16* wbase = WT + (j0 + lr) * HH + lg * 8;

#pragma unroll 2
  for (int ks = 0; ks < 8; ++ks) {
    half8 b[4];
#pragma unroll
    for (int rf = 0; rf < 4; ++rf)
      b[rf] = *(const half8*)(act + swz(rf * 16 + lr, ks * 32 + lg * 8));
#pragma unroll
    for (int jf = 0; jf < 4; ++jf) {
      half8 a = *(const half8*)(wbase + jf * 16 * HH + ks * 32);
#pragma unroll
      for (int rf = 0; rf < 4; ++rf)
        acc[jf][rf] = __builtin_amdgcn_mfma_f32_16x16x32_f16(a, b[rf], acc[jf][rf], 0, 0, 0);
    }
  }

  __syncthreads();

#pragma unroll
  for (int jf = 0; jf < 4; ++jf) {
    f32x4 bj = *(const f32x4*)(dbias + j0 + jf * 16 + lg * 4);
#pragma unroll
    for (int rf = 0; rf < 4; ++rf) {
      f32x4 v = acc[jf][rf] + bj;
      half4 h;
#pragma unroll
      for (int u = 0; u < 4; ++u)
        h[u] = (_Float16)fmaxf(v[u], 0.f);
      *(half4*)(act + swz(rf * 16 + lr, j0 + jf * 16 + lg * 4)) = h;
    }
  }
  __syncthreads();
}

// layer 1 via MFMA: F=3 -> H (relu), K padded 3 -> 32 with zeros.
__device__ __forceinline__ void layer1_mfma(char* act, const float* __restrict__ x,
                                            int r0g, const float* __restrict__ W0,
                                            const float* __restrict__ b0, int tid)
{
  const int wid  = tid >> 6;
  const int lane = tid & 63;
  const int lr   = lane & 15;
  const int lg   = lane >> 4;
  const int j0   = wid << 6;

  half8 a[4];
#pragma unroll
  for (int jf = 0; jf < 4; ++jf) {
    half8 v = {0, 0, 0, 0, 0, 0, 0, 0};
    if (lg == 0) {
      int j = j0 + jf * 16 + lr;
      v[0] = (_Float16)W0[j];
      v[1] = (_Float16)W0[HH + j];
      v[2] = (_Float16)W0[2 * HH + j];
    }
    a[jf] = v;
  }

  f32x4 acc[4][4];
#pragma unroll
  for (int jf = 0; jf < 4; ++jf)
#pragma unroll
    for (int rf = 0; rf < 4; ++rf)
      acc[jf][rf] = (f32x4){0.f, 0.f, 0.f, 0.f};

#pragma unroll
  for (int rf = 0; rf < 4; ++rf) {
    half8 b = {0, 0, 0, 0, 0, 0, 0, 0};
    if (lg == 0) {
      const float* xp = x + (size_t)(r0g + rf * 16 + lr) * 3;
      b[0] = (_Float16)xp[0];
      b[1] = (_Float16)xp[1];
      b[2] = (_Float16)xp[2];
    }
#pragma unroll
    for (int jf = 0; jf < 4; ++jf)
      acc[jf][rf] = __builtin_amdgcn_mfma_f32_16x16x32_f16(a[jf], b, acc[jf][rf], 0, 0, 0);
  }

#pragma unroll
  for (int jf = 0; jf < 4; ++jf) {
    f32x4 bj = *(const f32x4*)(b0 + j0 + jf * 16 + lg * 4);
#pragma unroll
    for (int rf = 0; rf < 4; ++rf) {
      f32x4 v = acc[jf][rf] + bj;
      half4 h;
#pragma unroll
      for (int u = 0; u < 4; ++u)
        h[u] = (_Float16)fmaxf(v[u], 0.f);
      *(half4*)(act + swz(rf * 16 + lr, j0 + jf * 16 + lg * 4)) = h;
    }
  }
  __syncthreads();
}

// ---------------------------------------------------------------------------
__global__ __launch_bounds__(THREADS, 2)
void trunk_kernel(const float* __restrict__ nodes, const int* __restrict__ coord_seg,
                  const float* __restrict__ tw0, const float* __restrict__ tb0,
                  const char* __restrict__ wt3_1, const float* __restrict__ tb1,
                  const char* __restrict__ wt3_2, const float* __restrict__ tb2,
                  float* __restrict__ seg_sum)
{
  __shared__ __align__(16) char act[ROWS * HH * 2];   // 32KB
  __shared__ __align__(16) char wpan[4 * 12288];      // 48KB
  const int tid = threadIdx.x;
  const int r0g = blockIdx.x * ROWS;

  layer1_mfma(act, nodes, r0g, tw0, tb0, tid);
  heavy_layer<0>(act, wpan, wt3_1, tb1, nullptr, nullptr, tid);
  heavy_layer<1>(act, wpan, wt3_2, tb2, nullptr, nullptr, tid);  // c

  {
    const int j = tid;
    const int s_lo = coord_seg[r0g];
    const int s_hi = coord_seg[r0g + ROWS - 1];
    if (s_lo == s_hi) {
      float p = 0.f;
#pragma unroll 8
      for (int r = 0; r < ROWS; ++r)
        p += (float)*(const _Float16*)(act + swz(r, j));
      atomicAdd(&seg_sum[s_lo * HH + j], p);
    } else {
      for (int s = s_lo; s <= s_hi; ++s) {
        float p = 0.f;
        for (int r = 0; r < ROWS; ++r)
          if (coord_seg[r0g + r] == s)
            p += (float)*(const _Float16*)(act + swz(r, j));
        atomicAdd(&seg_sum[s * HH + j], p);
      }
    }
  }
}

// d_s[s][j] = ob0[j] + sum_i bb2[i] * m_s[i] * ow0[i][j]
__global__ void dbias_kernel(const float* __restrict__ seg_mean,
                             const float* __restrict__ bb2,
                             const float* __restrict__ ow0,
                             const float* __restrict__ ob0,
                             float* __restrict__ d_s)
{
  const int s = blockIdx.x, j = threadIdx.x;
  float acc = ob0[j];
  for (int i = 0; i < HH; ++i)
    acc = fmaf(bb2[i] * seg_mean[s * HH + i], ow0[i * HH + j], acc);
  d_s[s * HH + j] = acc;
}

// C_s[j][k] = sum_i bw2[k][i] * m_s[i] * ow0[i][j]  (row-major [j][k] fp16)
// Block = (segment s, k-chunk of 64). act tile rows r' = scaled bw2 rows;
// A = wt3_ow0 DMA slabs (WT form of ow0). D[j][r'=k-local] -> C store.
__global__ __launch_bounds__(THREADS, 2)
void cfuse_kernel(const float* __restrict__ bw2, const float* __restrict__ seg_mean,
                  const char* __restrict__ wt3_ow0, _Float16* __restrict__ Cbuf)
{
  __shared__ __align__(16) char act[ROWS * HH * 2];
  __shared__ __align__(16) char wpan[4 * 12288];
  const int tid = threadIdx.x;
  const int s  = blockIdx.x >> 2;
  const int k0 = (blockIdx.x & 3) * 64;

  // build act tile: act[r'][i] = fp16(bw2[k0+r'][i] * m_s[i])
  {
    const int i = tid;
    const float mi = seg_mean[s * HH + i];
    for (int r = 0; r < ROWS; ++r)
      *(_Float16*)(act + swz(r, i)) = (_Float16)(bw2[(size_t)(k0 + r) * HH + i] * mi);
  }
  __syncthreads();

  const int wid  = tid >> 6;
  const int lane = tid & 63;
  const int lr   = lane & 15;
  const int lg   = lane >> 4;
  const int j0   = wid << 6;
  char* slab = wpan + wid * 12288;
  const char* wsrc = wt3_ow0 + wid * 4096;

  f32x4 acc[4][4];
#pragma unroll
  for (int jf = 0; jf < 4; ++jf)
#pragma unroll
    for (int rf = 0; rf < 4; ++rf)
      acc[jf][rf] = (f32x4){0.f, 0.f, 0.f, 0.f};

  stage_slab(wsrc + 0 * 16384, slab + 0 * 4096, lane);
  stage_slab(wsrc + 1 * 16384, slab + 1 * 4096, lane);
  stage_slab(wsrc + 2 * 16384, slab + 2 * 4096, lane);

  half8 a[2][4], b[2][4];
  asm volatile("s_waitcnt vmcnt(8)" ::: "memory");
  __builtin_amdgcn_sched_barrier(0);
#pragma unroll
  for (int rf = 0; rf < 4; ++rf)
    b[0][rf] = *(const half8*)(act + swz(rf * 16 + lr, 0 * 32 + lg * 8));
#pragma unroll
  for (int jf = 0; jf < 4; ++jf)
    a[0][jf] = *(const half8*)(slab + 0 * 4096 + jf * 1024 + lane * 16);

#pragma unroll
  for (int ks = 0; ks < 8; ++ks) {
    const int p = ks & 1;
    if (ks < 7) {
      if (ks < 6) asm volatile("s_waitcnt vmcnt(4)" ::: "memory");
      else        asm volatile("s_waitcnt vmcnt(0)" ::: "memory");
      __builtin_amdgcn_sched_barrier(0);
#pragma unroll
      for (int rf = 0; rf < 4; ++rf)
        b[p ^ 1][rf] = *(const half8*)(act + swz(rf * 16 + lr, (ks + 1) * 32 + lg * 8));
#pragma unroll
      for (int jf = 0; jf < 4; ++jf)
        a[p ^ 1][jf] = *(const half8*)(slab + ((ks + 1) % 3) * 4096 + jf * 1024 + lane * 16);
    }
    __builtin_amdgcn_sched_barrier(0);
#pragma unroll
    for (int jf = 0; jf < 4; ++jf)
#pragma unroll
      for (int rf = 0; rf < 4; ++rf)
        acc[jf][rf] = __builtin_amdgcn_mfma_f32_16x16x32_f16(a[p][jf], b[p][rf], acc[jf][rf], 0, 0, 0);
    __builtin_amdgcn_sched_barrier(0);
    if (ks < 5)
      stage_slab(wsrc + (ks + 3) * 16384, slab + (ks % 3) * 4096, lane);
  }

  _Float16* Cs = Cbuf + (size_t)s * HH * HH;
#pragma unroll
  for (int jf = 0; jf < 4; ++jf)
#pragma unroll
    for (int rf = 0; rf < 4; ++rf) {
      const int k = k0 + rf * 16 + lr;
#pragma unroll
      for (int u = 0; u < 4; ++u)
        Cs[(size_t)(j0 + jf * 16 + lg * 4 + u) * HH + k] = (_Float16)acc[jf][rf][u];
    }
}

__global__ __launch_bounds__(THREADS, 2)
void branch_kernel(const float* __restrict__ known_nodes, const int* __restrict__ known_seg,
                   const float* __restrict__ bw0, const float* __restrict__ bb0,
                   const char* __restrict__ wt3_1, const float* __restrict__ bb1,
                   const char* __restrict__ wt3_2, const float* __restrict__ bb2,
                   const float* __restrict__ seg_mean,
                   const char* __restrict__ wt3_o, const float* __restrict__ ob0,
                   const float* __restrict__ ow1, const float* __restrict__ ob1,
                   const _Float16* __restrict__ Cbuf, const float* __restrict__ d_s,
                   int use_fuse, float* __restrict__ out)
{
  __shared__ __align__(16) char act[ROWS * HH * 2];
  __shared__ __align__(16) char wpan[4 * 12288];
  const int tid = threadIdx.x;
  const int r0g = blockIdx.x * ROWS;

  layer1_mfma(act, known_nodes, r0g, bw0, bb0, tid);
  heavy_layer<0>(act, wpan, wt3_1, bb1, nullptr, nullptr, tid);

  const int s_lo = known_seg[r0g];
  const int s_hi = known_seg[r0g + ROWS - 1];
  if (use_fuse && s_lo == s_hi) {
    // fused: h = relu(C_s a + d_s) — replaces 2 heavy layers with 1
    stream_layer(act, Cbuf + (size_t)s_lo * HH * HH, d_s + s_lo * HH, tid);
  } else {
    heavy_layer<2>(act, wpan, wt3_2, bb2, seg_mean, known_seg + r0g, tid);
    heavy_layer<0>(act, wpan, wt3_o, ob0, nullptr, nullptr, tid);
  }

  // out = h @ ow1 + ob1 (256 -> 3): 256 threads, 4 k-quarters in parallel.
  float* ps = (float*)wpan;
  {
    const int r = tid & 63;
    const int q = tid >> 6;
    float o0 = 0.f, o1 = 0.f, o2 = 0.f;
    for (int kk = 0; kk < 64; kk += 8) {
      int k0 = q * 64 + kk;
      half8 h = *(const half8*)(act + swz(r, k0));
#pragma unroll
      for (int u = 0; u < 8; ++u) {
        float a = (float)h[u];
        o0 = fmaf(a, ow1[(k0 + u) * 3 + 0], o0);
        o1 = fmaf(a, ow1[(k0 + u) * 3 + 1], o1);
        o2 = fmaf(a, ow1[(k0 + u) * 3 + 2], o2);
      }
    }
    float* p = ps + q * ROWS * 3;
    p[r * 3 + 0] = o0; p[r * 3 + 1] = o1; p[r * 3 + 2] = o2;
  }
  __syncthreads();
  if (tid < ROWS) {
    const int r = tid;
    float* dst = out + (size_t)(r0g + r) * 3;
#pragma unroll
    for (int c = 0; c < 3; ++c) {
      float o = ob1[c];
#pragma unroll
      for (int q = 0; q < 4; ++q) o += ps[q * ROWS * 3 + r * 3 + c];
      dst[c] = o;
    }
  }
}

// W[256][256] fp32 (row=k, col=j) -> WT3 slab-linear fp16.
struct WPtrs { const float* w[5]; char* wt3[5]; };
__global__ void transpose_kernel(WPtrs p)
{
  const int m = blockIdx.x >> 8;
  const int k = blockIdx.x & 255;
  const int j = threadIdx.x;
  size_t off = (size_t)(k >> 5) * 16384 + (size_t)(j >> 6) * 4096
             + (size_t)((j >> 4) & 3) * 1024
             + (size_t)((((k >> 3) & 3) << 4) | (j & 15)) * 16
             + (size_t)(k & 7) * 2;
  *(_Float16*)(p.wt3[m] + off) = (_Float16)p.w[m][k * HH + j];
}

__global__ void zero_kernel(float* __restrict__ p, int n)
{
  int i = blockIdx.x * blockDim.x + threadIdx.x;
  if (i < n) p[i] = 0.f;
}

__global__ void mean_kernel(const float* __restrict__ seg_sum,
                            const int* __restrict__ coord_seg,
                            float* __restrict__ seg_mean)
{
  const int b = blockIdx.x;
  int lo = 0, n = NTOT;
  while (n > 0) { int h = n >> 1; int mid = lo + h;
    if (coord_seg[mid] < b) { lo = mid + 1; n -= h + 1; } else n = h; }
  int hi = lo; n = NTOT - lo;
  while (n > 0) { int h = n >> 1; int mid = hi + h;
    if (coord_seg[mid] < b + 1) { hi = mid + 1; n -= h + 1; } else n = h; }
  float inv = 1.0f / fmaxf((float)(hi - lo), 1.0f);
  seg_mean[b * HH + threadIdx.x] = seg_sum[b * HH + threadIdx.x] * inv;
}

// ---------------------------------------------------------------------------
extern "C" void kernel_launch(void* const* d_in, const int* in_sizes, int n_in,
                              void* d_out, int out_size, void* d_ws, size_t ws_size,
                              hipStream_t stream)
{
  const float* known_nodes = (const float*)d_in[0];
  const float* nodes       = (const float*)d_in[1];
  const int*   known_seg   = (const int*)d_in[2];
  const int*   coord_seg   = (const int*)d_in[3];
  const float* bw0 = (const float*)d_in[4];
  const float* bb0 = (const float*)d_in[5];
  const float* bw1 = (const float*)d_in[6];
  const float* bb1 = (const float*)d_in[7];
  const float* bw2 = (const float*)d_in[8];
  const float* bb2 = (const float*)d_in[9];
  const float* tw0 = (const float*)d_in[10];
  const float* tb0 = (const float*)d_in[11];
  const float* tw1 = (const float*)d_in[12];
  const float* tb1 = (const float*)d_in[13];
  const float* tw2 = (const float*)d_in[14];
  const float* tb2 = (const float*)d_in[15];
  const float* ow0 = (const float*)d_in[16];
  const float* ob0 = (const float*)d_in[17];
  const float* ow1 = (const float*)d_in[18];
  const float* ob1 = (const float*)d_in[19];

  float* out      = (float*)d_out;
  char* p = (char*)d_ws;
  float* seg_sum  = (float*)p;            p += (size_t)NB * HH * 4;   // 64KB
  float* seg_mean = (float*)p;            p += (size_t)NB * HH * 4;   // 64KB
  char* wt3_tw1 = p;  p += (size_t)HH * HH * 2;
  char* wt3_tw2 = p;  p += (size_t)HH * HH * 2;
  char* wt3_bw1 = p;  p += (size_t)HH * HH * 2;
  char* wt3_bw2 = p;  p += (size_t)HH * HH * 2;
  char* wt3_ow0 = p;  p += (size_t)HH * HH * 2;
  float* d_s    = (float*)p;              p += (size_t)NB * HH * 4;   // 64KB
  _Float16* Cbuf = (_Float16*)p;          p += (size_t)NB * HH * HH * 2;  // 8MB
  const int use_fuse = ((size_t)(p - (char*)d_ws) <= ws_size) ? 1 : 0;

  WPtrs wp;
  wp.w[0] = tw1; wp.wt3[0] = wt3_tw1;
  wp.w[1] = tw2; wp.wt3[1] = wt3_tw2;
  wp.w[2] = bw1; wp.wt3[2] = wt3_bw1;
  wp.w[3] = bw2; wp.wt3[3] = wt3_bw2;
  wp.w[4] = ow0; wp.wt3[4] = wt3_ow0;

  transpose_kernel<<<5 * 256, 256, 0, stream>>>(wp);
  zero_kernel<<<(NB * HH + 255) / 256, 256, 0, stream>>>(seg_sum, NB * HH);
  trunk_kernel<<<NTOT / ROWS, THREADS, 0, stream>>>(nodes, coord_seg,
                                                    tw0, tb0, wt3_tw1, tb1, wt3_tw2, tb2,
                                                    seg_sum);
  mean_kernel<<<NB, 256, 0, stream>>>(seg_sum, coord_seg, seg_mean);
  if (use_fuse) {
    dbias_kernel<<<NB, 256, 0, stream>>>(seg_mean, bb2, ow0, ob0, d_s);
    cfuse_kernel<<<NB * 4, THREADS, 0, stream>>>(bw2, seg_mean, wt3_ow0, Cbuf);
  }
  branch_kernel<<<NTOT / ROWS, THREADS, 0, stream>>>(known_nodes, known_seg,
                                                     bw0, bb0, wt3_bw1, bb1, wt3_bw2, bb2,
                                                     seg_mean,
                                                     wt3_ow0, ob0, ow1, ob1,
                                                     Cbuf, d_s, use_fuse,
                                                     out);
}

// Round 22
// 245.249 us; speedup vs baseline: 1.1596x; 1.1596x over previous
//
#include <hip/hip_runtime.h>

#define HH 256       // hidden size
#define NB 64        // batch (segments)
#define ROWS 64      // rows per block tile
#define NTOT 262144  // NK == NC
#define THREADS 256  // 4 waves

typedef _Float16 half8 __attribute__((ext_vector_type(8)));
typedef _Float16 half4 __attribute__((ext_vector_type(4)));
typedef float f32x4 __attribute__((ext_vector_type(4)));

typedef __attribute__((address_space(1))) const void gas_t;
typedef __attribute__((address_space(3))) void las_t;

// act LDS tile: [row][k] fp16, 64 rows x 256 k = 32KB, row stride 512B.
__device__ __forceinline__ uint32_t swz(uint32_t r, uint32_t k) {
  return (((r << 9) + (k << 1)) ^ ((r & 7) << 4)) ^ ((r & 8) << 3);
}

// Stage one wave-private 4KB A-slab (64 j x 32 k): 4 DMA calls x 1KB.
__device__ __forceinline__ void stage_slab(const char* __restrict__ g, char* l,
                                           int lane)
{
  const char* gp = g + lane * 16;
#pragma unroll
  for (int c = 0; c < 4; ++c)
    __builtin_amdgcn_global_load_lds((gas_t*)(gp + c * 1024), (las_t*)(l + c * 1024),
                                     16, 0, 0);
}

// ---------------------------------------------------------------------------
// R17 heavy layer (best measured): MFMA swapped operands, A from wave-private
// DMA slabs (3-deep, counted vmcnt), both operands double-buffered in regs.
// MODE: 0 relu; 1 plain; 2 multiply seg_mean[seg_g[r]] (branch mixed path)
// ---------------------------------------------------------------------------
template<int MODE>
__device__ __forceinline__ void heavy_layer(char* act, char* wpan,
                                            const char* __restrict__ wt3,
                                            const float* __restrict__ bias,
                                            const float* __restrict__ seg_mean,
                                            const int* __restrict__ seg_g, int tid)
{
  const int wid  = tid >> 6;
  const int lane = tid & 63;
  const int lr   = lane & 15;
  const int lg   = lane >> 4;
  const int j0   = wid << 6;
  char* slab = wpan + wid * 12288;
  const char* wsrc = wt3 + wid * 4096;

  f32x4 acc[4][4];
#pragma unroll
  for (int jf = 0; jf < 4; ++jf)
#pragma unroll
    for (int rf = 0; rf < 4; ++rf)
      acc[jf][rf] = (f32x4){0.f, 0.f, 0.f, 0.f};

  stage_slab(wsrc + 0 * 16384, slab + 0 * 4096, lane);
  stage_slab(wsrc + 1 * 16384, slab + 1 * 4096, lane);
  stage_slab(wsrc + 2 * 16384, slab + 2 * 4096, lane);

  half8 a[2][4], b[2][4];

  asm volatile("s_waitcnt vmcnt(8)" ::: "memory");
  __builtin_amdgcn_sched_barrier(0);
#pragma unroll
  for (int rf = 0; rf < 4; ++rf)
    b[0][rf] = *(const half8*)(act + swz(rf * 16 + lr, 0 * 32 + lg * 8));
#pragma unroll
  for (int jf = 0; jf < 4; ++jf)
    a[0][jf] = *(const half8*)(slab + 0 * 4096 + jf * 1024 + lane * 16);

#pragma unroll
  for (int ks = 0; ks < 8; ++ks) {
    const int p = ks & 1;
    if (ks < 7) {
      if (ks < 6) asm volatile("s_waitcnt vmcnt(4)" ::: "memory");
      else        asm volatile("s_waitcnt vmcnt(0)" ::: "memory");
      __builtin_amdgcn_sched_barrier(0);
#pragma unroll
      for (int rf = 0; rf < 4; ++rf)
        b[p ^ 1][rf] = *(const half8*)(act + swz(rf * 16 + lr, (ks + 1) * 32 + lg * 8));
#pragma unroll
      for (int jf = 0; jf < 4; ++jf)
        a[p ^ 1][jf] = *(const half8*)(slab + ((ks + 1) % 3) * 4096 + jf * 1024 + lane * 16);
    }
    __builtin_amdgcn_sched_barrier(0);
#pragma unroll
    for (int jf = 0; jf < 4; ++jf)
#pragma unroll
      for (int rf = 0; rf < 4; ++rf)
        acc[jf][rf] = __builtin_amdgcn_mfma_f32_16x16x32_f16(a[p][jf], b[p][rf], acc[jf][rf], 0, 0, 0);
    __builtin_amdgcn_sched_barrier(0);
    if (ks < 5)
      stage_slab(wsrc + (ks + 3) * 16384, slab + (ks % 3) * 4096, lane);
  }

  int sseg[4];
  if (MODE == 2) {
#pragma unroll
    for (int rf = 0; rf < 4; ++rf) sseg[rf] = seg_g[rf * 16 + lr];
  }

  __syncthreads();  // all waves done READING act before overwrite

#pragma unroll
  for (int jf = 0; jf < 4; ++jf) {
    f32x4 bj = *(const f32x4*)(bias + j0 + jf * 16 + lg * 4);
#pragma unroll
    for (int rf = 0; rf < 4; ++rf) {
      f32x4 v = acc[jf][rf] + bj;
      if (MODE == 2) {
        f32x4 sm = *(const f32x4*)(seg_mean + sseg[rf] * HH + j0 + jf * 16 + lg * 4);
        v *= sm;
      }
      half4 h;
#pragma unroll
      for (int u = 0; u < 4; ++u) {
        float x = v[u];
        if (MODE == 0) x = fmaxf(x, 0.f);
        h[u] = (_Float16)x;
      }
      *(half4*)(act + swz(rf * 16 + lr, j0 + jf * 16 + lg * 4)) = h;
    }
  }
  __syncthreads();
}

// layer 1 via MFMA: F=3 -> H (relu), K padded 3 -> 32 with zeros.
__device__ __forceinline__ void layer1_mfma(char* act, const float* __restrict__ x,
                                            int r0g, const float* __restrict__ W0,
                                            const float* __restrict__ b0, int tid)
{
  const int wid  = tid >> 6;
  const int lane = tid & 63;
  const int lr   = lane & 15;
  const int lg   = lane >> 4;
  const int j0   = wid << 6;

  half8 a[4];
#pragma unroll
  for (int jf = 0; jf < 4; ++jf) {
    half8 v = {0, 0, 0, 0, 0, 0, 0, 0};
    if (lg == 0) {
      int j = j0 + jf * 16 + lr;
      v[0] = (_Float16)W0[j];
      v[1] = (_Float16)W0[HH + j];
      v[2] = (_Float16)W0[2 * HH + j];
    }
    a[jf] = v;
  }

  f32x4 acc[4][4];
#pragma unroll
  for (int jf = 0; jf < 4; ++jf)
#pragma unroll
    for (int rf = 0; rf < 4; ++rf)
      acc[jf][rf] = (f32x4){0.f, 0.f, 0.f, 0.f};

#pragma unroll
  for (int rf = 0; rf < 4; ++rf) {
    half8 b = {0, 0, 0, 0, 0, 0, 0, 0};
    if (lg == 0) {
      const float* xp = x + (size_t)(r0g + rf * 16 + lr) * 3;
      b[0] = (_Float16)xp[0];
      b[1] = (_Float16)xp[1];
      b[2] = (_Float16)xp[2];
    }
#pragma unroll
    for (int jf = 0; jf < 4; ++jf)
      acc[jf][rf] = __builtin_amdgcn_mfma_f32_16x16x32_f16(a[jf], b, acc[jf][rf], 0, 0, 0);
  }

#pragma unroll
  for (int jf = 0; jf < 4; ++jf) {
    f32x4 bj = *(const f32x4*)(b0 + j0 + jf * 16 + lg * 4);
#pragma unroll
    for (int rf = 0; rf < 4; ++rf) {
      f32x4 v = acc[jf][rf] + bj;
      half4 h;
#pragma unroll
      for (int u = 0; u < 4; ++u)
        h[u] = (_Float16)fmaxf(v[u], 0.f);
      *(half4*)(act + swz(rf * 16 + lr, j0 + jf * 16 + lg * 4)) = h;
    }
  }
  __syncthreads();
}

// ---------------------------------------------------------------------------
__global__ __launch_bounds__(THREADS, 2)
void trunk_kernel(const float* __restrict__ nodes, const int* __restrict__ coord_seg,
                  const float* __restrict__ tw0, const float* __restrict__ tb0,
                  const char* __restrict__ wt3_1, const float* __restrict__ tb1,
                  const char* __restrict__ wt3_2, const float* __restrict__ tb2,
                  float* __restrict__ seg_sum)
{
  __shared__ __align__(16) char act[ROWS * HH * 2];   // 32KB
  __shared__ __align__(16) char wpan[4 * 12288];      // 48KB
  const int tid = threadIdx.x;
  const int r0g = blockIdx.x * ROWS;

  layer1_mfma(act, nodes, r0g, tw0, tb0, tid);
  heavy_layer<0>(act, wpan, wt3_1, tb1, nullptr, nullptr, tid);
  heavy_layer<1>(act, wpan, wt3_2, tb2, nullptr, nullptr, tid);  // c

  {
    const int j = tid;
    const int s_lo = coord_seg[r0g];
    const int s_hi = coord_seg[r0g + ROWS - 1];
    if (s_lo == s_hi) {
      float p = 0.f;
#pragma unroll 8
      for (int r = 0; r < ROWS; ++r)
        p += (float)*(const _Float16*)(act + swz(r, j));
      atomicAdd(&seg_sum[s_lo * HH + j], p);
    } else {
      for (int s = s_lo; s <= s_hi; ++s) {
        float p = 0.f;
        for (int r = 0; r < ROWS; ++r)
          if (coord_seg[r0g + r] == s)
            p += (float)*(const _Float16*)(act + swz(r, j));
        atomicAdd(&seg_sum[s * HH + j], p);
      }
    }
  }
}

// d_s[s][j] = ob0[j] + sum_i bb2[i] * m_s[i] * ow0[i][j]
__global__ void dbias_kernel(const float* __restrict__ seg_mean,
                             const float* __restrict__ bb2,
                             const float* __restrict__ ow0,
                             const float* __restrict__ ob0,
                             float* __restrict__ d_s)
{
  const int s = blockIdx.x, j = threadIdx.x;
  float acc = ob0[j];
  for (int i = 0; i < HH; ++i)
    acc = fmaf(bb2[i] * seg_mean[s * HH + i], ow0[i * HH + j], acc);
  d_s[s * HH + j] = acc;
}

// C_s[j][k] = sum_i bw2[k][i]*m_s[i]*ow0[i][j], written DIRECTLY in WT3
// slab-linear layout (so branch can DMA it like any other weight).
// Block = (s, k-chunk kc of 64). Phase A: act[r'][i] = bw2[k0+r'][i]*m_s[i].
// Phase B: heavy MFMA with wt3_ow0. Phase C: D-frags -> dbuf[j][k'] in LDS
// (XOR-swizzled rows). Phase D: coalesced 16B stores in slab-linear order.
__global__ __launch_bounds__(THREADS, 2)
void cfuse_kernel(const float* __restrict__ bw2, const float* __restrict__ seg_mean,
                  const char* __restrict__ wt3_ow0, char* __restrict__ Cbuf)
{
  __shared__ __align__(16) char act[ROWS * HH * 2];
  __shared__ __align__(16) char wpan[4 * 12288];
  const int tid = threadIdx.x;
  const int s  = blockIdx.x >> 2;
  const int kc = blockIdx.x & 3;
  const int k0 = kc * 64;

  // Phase A
  {
    const int i = tid;
    const float mi = seg_mean[s * HH + i];
    for (int r = 0; r < ROWS; ++r)
      *(_Float16*)(act + swz(r, i)) = (_Float16)(bw2[(size_t)(k0 + r) * HH + i] * mi);
  }
  __syncthreads();

  const int wid  = tid >> 6;
  const int lane = tid & 63;
  const int lr   = lane & 15;
  const int lg   = lane >> 4;
  const int j0   = wid << 6;
  char* slab = wpan + wid * 12288;
  const char* wsrc = wt3_ow0 + wid * 4096;

  f32x4 acc[4][4];
#pragma unroll
  for (int jf = 0; jf < 4; ++jf)
#pragma unroll
    for (int rf = 0; rf < 4; ++rf)
      acc[jf][rf] = (f32x4){0.f, 0.f, 0.f, 0.f};

  stage_slab(wsrc + 0 * 16384, slab + 0 * 4096, lane);
  stage_slab(wsrc + 1 * 16384, slab + 1 * 4096, lane);
  stage_slab(wsrc + 2 * 16384, slab + 2 * 4096, lane);

  half8 a[2][4], b[2][4];
  asm volatile("s_waitcnt vmcnt(8)" ::: "memory");
  __builtin_amdgcn_sched_barrier(0);
#pragma unroll
  for (int rf = 0; rf < 4; ++rf)
    b[0][rf] = *(const half8*)(act + swz(rf * 16 + lr, 0 * 32 + lg * 8));
#pragma unroll
  for (int jf = 0; jf < 4; ++jf)
    a[0][jf] = *(const half8*)(slab + 0 * 4096 + jf * 1024 + lane * 16);

#pragma unroll
  for (int ks = 0; ks < 8; ++ks) {
    const int p = ks & 1;
    if (ks < 7) {
      if (ks < 6) asm volatile("s_waitcnt vmcnt(4)" ::: "memory");
      else        asm volatile("s_waitcnt vmcnt(0)" ::: "memory");
      __builtin_amdgcn_sched_barrier(0);
#pragma unroll
      for (int rf = 0; rf < 4; ++rf)
        b[p ^ 1][rf] = *(const half8*)(act + swz(rf * 16 + lr, (ks + 1) * 32 + lg * 8));
#pragma unroll
      for (int jf = 0; jf < 4; ++jf)
        a[p ^ 1][jf] = *(const half8*)(slab + ((ks + 1) % 3) * 4096 + jf * 1024 + lane * 16);
    }
    __builtin_amdgcn_sched_barrier(0);
#pragma unroll
    for (int jf = 0; jf < 4; ++jf)
#pragma unroll
      for (int rf = 0; rf < 4; ++rf)
        acc[jf][rf] = __builtin_amdgcn_mfma_f32_16x16x32_f16(a[p][jf], b[p][rf], acc[jf][rf], 0, 0, 0);
    __builtin_amdgcn_sched_barrier(0);
    if (ks < 5)
      stage_slab(wsrc + (ks + 3) * 16384, slab + (ks % 3) * 4096, lane);
  }
  // all DMAs retired (vmcnt 0 at ks=6 wait) -> wpan reusable as dbuf.

  // Phase C: dbuf[j][k'] fp16, row stride 128B, byte = j*128 + (k'*2 ^ ((j&7)<<4))
  char* dbuf = wpan;
#pragma unroll
  for (int jf = 0; jf < 4; ++jf)
#pragma unroll
    for (int rf = 0; rf < 4; ++rf) {
      const int kl = rf * 16 + lr;
#pragma unroll
      for (int u = 0; u < 4; ++u) {
        const int j = j0 + jf * 16 + lg * 4 + u;
        *(_Float16*)(dbuf + j * 128 + ((kl * 2) ^ ((j & 7) << 4))) = (_Float16)acc[jf][rf][u];
      }
    }
  __syncthreads();

  // Phase D: coalesced copy-out in slab-linear order. 32KB total, thread t
  // writes 8 x 16B chunks at g = c*4096 + t*16.
  char* Cdst = Cbuf + (size_t)s * 131072 + (size_t)(kc * 2) * 16384;
#pragma unroll
  for (int c = 0; c < 8; ++c) {
    const uint32_t g = c * 4096 + tid * 16;
    const uint32_t sl = g >> 14;         // 0 or 1 (slab within pair)
    const uint32_t aa = g & 16383;
    const uint32_t wq = aa >> 12;
    const uint32_t jjf = (aa >> 10) & 3;
    const uint32_t l  = (aa >> 4) & 63;
    const uint32_t j  = wq * 64 + jjf * 16 + (l & 15);
    const uint32_t kl = sl * 32 + ((l >> 4) << 3);
    uint4 v = *(const uint4*)(dbuf + j * 128 + ((kl * 2) ^ ((j & 7) << 4)));
    *(uint4*)(Cdst + sl * 16384 + aa) = v;
  }
}

__global__ __launch_bounds__(THREADS, 2)
void branch_kernel(const float* __restrict__ known_nodes, const int* __restrict__ known_seg,
                   const float* __restrict__ bw0, const float* __restrict__ bb0,
                   const char* __restrict__ wt3_1, const float* __restrict__ bb1,
                   const char* __restrict__ wt3_2, const float* __restrict__ bb2,
                   const float* __restrict__ seg_mean,
                   const char* __restrict__ wt3_o, const float* __restrict__ ob0,
                   const float* __restrict__ ow1, const float* __restrict__ ob1,
                   const char* __restrict__ Cbuf, const float* __restrict__ d_s,
                   int use_fuse, float* __restrict__ out)
{
  __shared__ __align__(16) char act[ROWS * HH * 2];
  __shared__ __align__(16) char wpan[4 * 12288];
  const int tid = threadIdx.x;
  // XCD-aware bijective swizzle (4096 % 8 == 0): same-segment blocks share an
  // XCD -> each L2 caches only its ~1MB slice of Cbuf.
  const int bid = ((int)blockIdx.x & 7) * ((int)gridDim.x >> 3) + ((int)blockIdx.x >> 3);
  const int r0g = bid * ROWS;

  layer1_mfma(act, known_nodes, r0g, bw0, bb0, tid);
  heavy_layer<0>(act, wpan, wt3_1, bb1, nullptr, nullptr, tid);

  const int s_lo = known_seg[r0g];
  const int s_hi = known_seg[r0g + ROWS - 1];
  if (use_fuse && s_lo == s_hi) {
    // fused: h = relu(C_s a + d_s) via the standard DMA-slab layer
    heavy_layer<0>(act, wpan, Cbuf + (size_t)s_lo * 131072, d_s + s_lo * HH,
                   nullptr, nullptr, tid);
  } else {
    heavy_layer<2>(act, wpan, wt3_2, bb2, seg_mean, known_seg + r0g, tid);
    heavy_layer<0>(act, wpan, wt3_o, ob0, nullptr, nullptr, tid);
  }

  // out = h @ ow1 + ob1 (256 -> 3): 256 threads, 4 k-quarters in parallel.
  float* ps = (float*)wpan;
  {
    const int r = tid & 63;
    const int q = tid >> 6;
    float o0 = 0.f, o1 = 0.f, o2 = 0.f;
    for (int kk = 0; kk < 64; kk += 8) {
      int k0 = q * 64 + kk;
      half8 h = *(const half8*)(act + swz(r, k0));
#pragma unroll
      for (int u = 0; u < 8; ++u) {
        float a = (float)h[u];
        o0 = fmaf(a, ow1[(k0 + u) * 3 + 0], o0);
        o1 = fmaf(a, ow1[(k0 + u) * 3 + 1], o1);
        o2 = fmaf(a, ow1[(k0 + u) * 3 + 2], o2);
      }
    }
    float* p = ps + q * ROWS * 3;
    p[r * 3 + 0] = o0; p[r * 3 + 1] = o1; p[r * 3 + 2] = o2;
  }
  __syncthreads();
  if (tid < ROWS) {
    const int r = tid;
    float* dst = out + (size_t)(r0g + r) * 3;
#pragma unroll
    for (int c = 0; c < 3; ++c) {
      float o = ob1[c];
#pragma unroll
      for (int q = 0; q < 4; ++q) o += ps[q * ROWS * 3 + r * 3 + c];
      dst[c] = o;
    }
  }
}

// W[256][256] fp32 (row=k, col=j) -> WT3 slab-linear fp16.
struct WPtrs { const float* w[5]; char* wt3[5]; };
__global__ void transpose_kernel(WPtrs p)
{
  const int m = blockIdx.x >> 8;
  const int k = blockIdx.x & 255;
  const int j = threadIdx.x;
  size_t off = (size_t)(k >> 5) * 16384 + (size_t)(j >> 6) * 4096
             + (size_t)((j >> 4) & 3) * 1024
             + (size_t)((((k >> 3) & 3) << 4) | (j & 15)) * 16
             + (size_t)(k & 7) * 2;
  *(_Float16*)(p.wt3[m] + off) = (_Float16)p.w[m][k * HH + j];
}

__global__ void zero_kernel(float* __restrict__ p, int n)
{
  int i = blockIdx.x * blockDim.x + threadIdx.x;
  if (i < n) p[i] = 0.f;
}

__global__ void mean_kernel(const float* __restrict__ seg_sum,
                            const int* __restrict__ coord_seg,
                            float* __restrict__ seg_mean)
{
  const int b = blockIdx.x;
  int lo = 0, n = NTOT;
  while (n > 0) { int h = n >> 1; int mid = lo + h;
    if (coord_seg[mid] < b) { lo = mid + 1; n -= h + 1; } else n = h; }
  int hi = lo; n = NTOT - lo;
  while (n > 0) { int h = n >> 1; int mid = hi + h;
    if (coord_seg[mid] < b + 1) { hi = mid + 1; n -= h + 1; } else n = h; }
  float inv = 1.0f / fmaxf((float)(hi - lo), 1.0f);
  seg_mean[b * HH + threadIdx.x] = seg_sum[b * HH + threadIdx.x] * inv;
}

// ---------------------------------------------------------------------------
extern "C" void kernel_launch(void* const* d_in, const int* in_sizes, int n_in,
                              void* d_out, int out_size, void* d_ws, size_t ws_size,
                              hipStream_t stream)
{
  const float* known_nodes = (const float*)d_in[0];
  const float* nodes       = (const float*)d_in[1];
  const int*   known_seg   = (const int*)d_in[2];
  const int*   coord_seg   = (const int*)d_in[3];
  const float* bw0 = (const float*)d_in[4];
  const float* bb0 = (const float*)d_in[5];
  const float* bw1 = (const float*)d_in[6];
  const float* bb1 = (const float*)d_in[7];
  const float* bw2 = (const float*)d_in[8];
  const float* bb2 = (const float*)d_in[9];
  const float* tw0 = (const float*)d_in[10];
  const float* tb0 = (const float*)d_in[11];
  const float* tw1 = (const float*)d_in[12];
  const float* tb1 = (const float*)d_in[13];
  const float* tw2 = (const float*)d_in[14];
  const float* tb2 = (const float*)d_in[15];
  const float* ow0 = (const float*)d_in[16];
  const float* ob0 = (const float*)d_in[17];
  const float* ow1 = (const float*)d_in[18];
  const float* ob1 = (const float*)d_in[19];

  float* out      = (float*)d_out;
  char* p = (char*)d_ws;
  float* seg_sum  = (float*)p;            p += (size_t)NB * HH * 4;
  float* seg_mean = (float*)p;            p += (size_t)NB * HH * 4;
  char* wt3_tw1 = p;  p += (size_t)HH * HH * 2;
  char* wt3_tw2 = p;  p += (size_t)HH * HH * 2;
  char* wt3_bw1 = p;  p += (size_t)HH * HH * 2;
  char* wt3_bw2 = p;  p += (size_t)HH * HH * 2;
  char* wt3_ow0 = p;  p += (size_t)HH * HH * 2;
  float* d_s    = (float*)p;              p += (size_t)NB * HH * 4;
  char* Cbuf    = p;                      p += (size_t)NB * HH * HH * 2;  // 8MB
  const int use_fuse = ((size_t)(p - (char*)d_ws) <= ws_size) ? 1 : 0;

  WPtrs wp;
  wp.w[0] = tw1; wp.wt3[0] = wt3_tw1;
  wp.w[1] = tw2; wp.wt3[1] = wt3_tw2;
  wp.w[2] = bw1; wp.wt3[2] = wt3_bw1;
  wp.w[3] = bw2; wp.wt3[3] = wt3_bw2;
  wp.w[4] = ow0; wp.wt3[4] = wt3_ow0;

  transpose_kernel<<<5 * 256, 256, 0, stream>>>(wp);
  zero_kernel<<<(NB * HH + 255) / 256, 256, 0, stream>>>(seg_sum, NB * HH);
  trunk_kernel<<<NTOT / ROWS, THREADS, 0, stream>>>(nodes, coord_seg,
                                                    tw0, tb0, wt3_tw1, tb1, wt3_tw2, tb2,
                                                    seg_sum);
  mean_kernel<<<NB, 256, 0, stream>>>(seg_sum, coord_seg, seg_mean);
  if (use_fuse) {
    dbias_kernel<<<NB, 256, 0, stream>>>(seg_mean, bb2, ow0, ob0, d_s);
    cfuse_kernel<<<NB * 4, THREADS, 0, stream>>>(bw2, seg_mean, wt3_ow0, Cbuf);
  }
  branch_kernel<<<NTOT / ROWS, THREADS, 0, stream>>>(known_nodes, known_seg,
                                                     bw0, bb0, wt3_bw1, bb1, wt3_bw2, bb2,
                                                     seg_mean,
                                                     wt3_ow0, ob0, ow1, ob1,
                                                     Cbuf, d_s, use_fuse,
                                                     out);
}

// Round 23
// 222.813 us; speedup vs baseline: 1.2764x; 1.1007x over previous
//
#include <hip/hip_runtime.h>

#define HH 256       // hidden size
#define NB 64        // batch (segments)
#define ROWS 64      // rows per block tile
#define NTOT 262144  // NK == NC
#define THREADS 256  // 4 waves

typedef _Float16 half8 __attribute__((ext_vector_type(8)));
typedef _Float16 half4 __attribute__((ext_vector_type(4)));
typedef float f32x4 __attribute__((ext_vector_type(4)));

typedef __attribute__((address_space(1))) const void gas_t;
typedef __attribute__((address_space(3))) void las_t;

// act LDS tile: [row][k] fp16, 64 rows x 256 k = 32KB, row stride 512B.
__device__ __forceinline__ uint32_t swz(uint32_t r, uint32_t k) {
  return (((r << 9) + (k << 1)) ^ ((r & 7) << 4)) ^ ((r & 8) << 3);
}

// Stage one wave-private 4KB A-slab (64 j x 32 k): 4 DMA calls x 1KB.
__device__ __forceinline__ void stage_slab(const char* __restrict__ g, char* l,
                                           int lane)
{
  const char* gp = g + lane * 16;
#pragma unroll
  for (int c = 0; c < 4; ++c)
    __builtin_amdgcn_global_load_lds((gas_t*)(gp + c * 1024), (las_t*)(l + c * 1024),
                                     16, 0, 0);
}

// ---------------------------------------------------------------------------
// R17 heavy layer (best measured): MFMA swapped operands, A from wave-private
// DMA slabs (3-deep, counted vmcnt), both operands double-buffered in regs.
// MODE: 0 relu; 1 plain; 2 multiply seg_mean[seg_g[r]] (branch mixed path)
// ---------------------------------------------------------------------------
template<int MODE>
__device__ __forceinline__ void heavy_layer(char* act, char* wpan,
                                            const char* __restrict__ wt3,
                                            const float* __restrict__ bias,
                                            const float* __restrict__ seg_mean,
                                            const int* __restrict__ seg_g, int tid)
{
  const int wid  = tid >> 6;
  const int lane = tid & 63;
  const int lr   = lane & 15;
  const int lg   = lane >> 4;
  const int j0   = wid << 6;
  char* slab = wpan + wid * 12288;
  const char* wsrc = wt3 + wid * 4096;

  f32x4 acc[4][4];
#pragma unroll
  for (int jf = 0; jf < 4; ++jf)
#pragma unroll
    for (int rf = 0; rf < 4; ++rf)
      acc[jf][rf] = (f32x4){0.f, 0.f, 0.f, 0.f};

  stage_slab(wsrc + 0 * 16384, slab + 0 * 4096, lane);
  stage_slab(wsrc + 1 * 16384, slab + 1 * 4096, lane);
  stage_slab(wsrc + 2 * 16384, slab + 2 * 4096, lane);

  half8 a[2][4], b[2][4];

  asm volatile("s_waitcnt vmcnt(8)" ::: "memory");
  __builtin_amdgcn_sched_barrier(0);
#pragma unroll
  for (int rf = 0; rf < 4; ++rf)
    b[0][rf] = *(const half8*)(act + swz(rf * 16 + lr, 0 * 32 + lg * 8));
#pragma unroll
  for (int jf = 0; jf < 4; ++jf)
    a[0][jf] = *(const half8*)(slab + 0 * 4096 + jf * 1024 + lane * 16);

#pragma unroll
  for (int ks = 0; ks < 8; ++ks) {
    const int p = ks & 1;
    if (ks < 7) {
      if (ks < 6) asm volatile("s_waitcnt vmcnt(4)" ::: "memory");
      else        asm volatile("s_waitcnt vmcnt(0)" ::: "memory");
      __builtin_amdgcn_sched_barrier(0);
#pragma unroll
      for (int rf = 0; rf < 4; ++rf)
        b[p ^ 1][rf] = *(const half8*)(act + swz(rf * 16 + lr, (ks + 1) * 32 + lg * 8));
#pragma unroll
      for (int jf = 0; jf < 4; ++jf)
        a[p ^ 1][jf] = *(const half8*)(slab + ((ks + 1) % 3) * 4096 + jf * 1024 + lane * 16);
    }
    __builtin_amdgcn_sched_barrier(0);
#pragma unroll
    for (int jf = 0; jf < 4; ++jf)
#pragma unroll
      for (int rf = 0; rf < 4; ++rf)
        acc[jf][rf] = __builtin_amdgcn_mfma_f32_16x16x32_f16(a[p][jf], b[p][rf], acc[jf][rf], 0, 0, 0);
    __builtin_amdgcn_sched_barrier(0);
    if (ks < 5)
      stage_slab(wsrc + (ks + 3) * 16384, slab + (ks % 3) * 4096, lane);
  }

  int sseg[4];
  if (MODE == 2) {
#pragma unroll
    for (int rf = 0; rf < 4; ++rf) sseg[rf] = seg_g[rf * 16 + lr];
  }

  __syncthreads();  // all waves done READING act before overwrite

#pragma unroll
  for (int jf = 0; jf < 4; ++jf) {
    f32x4 bj = *(const f32x4*)(bias + j0 + jf * 16 + lg * 4);
#pragma unroll
    for (int rf = 0; rf < 4; ++rf) {
      f32x4 v = acc[jf][rf] + bj;
      if (MODE == 2) {
        f32x4 sm = *(const f32x4*)(seg_mean + sseg[rf] * HH + j0 + jf * 16 + lg * 4);
        v *= sm;
      }
      half4 h;
#pragma unroll
      for (int u = 0; u < 4; ++u) {
        float x = v[u];
        if (MODE == 0) x = fmaxf(x, 0.f);
        h[u] = (_Float16)x;
      }
      *(half4*)(act + swz(rf * 16 + lr, j0 + jf * 16 + lg * 4)) = h;
    }
  }
  __syncthreads();
}

// layer 1 via MFMA: F=3 -> H (relu), K padded 3 -> 32 with zeros.
__device__ __forceinline__ void layer1_mfma(char* act, const float* __restrict__ x,
                                            int r0g, const float* __restrict__ W0,
                                            const float* __restrict__ b0, int tid)
{
  const int wid  = tid >> 6;
  const int lane = tid & 63;
  const int lr   = lane & 15;
  const int lg   = lane >> 4;
  const int j0   = wid << 6;

  half8 a[4];
#pragma unroll
  for (int jf = 0; jf < 4; ++jf) {
    half8 v = {0, 0, 0, 0, 0, 0, 0, 0};
    if (lg == 0) {
      int j = j0 + jf * 16 + lr;
      v[0] = (_Float16)W0[j];
      v[1] = (_Float16)W0[HH + j];
      v[2] = (_Float16)W0[2 * HH + j];
    }
    a[jf] = v;
  }

  f32x4 acc[4][4];
#pragma unroll
  for (int jf = 0; jf < 4; ++jf)
#pragma unroll
    for (int rf = 0; rf < 4; ++rf)
      acc[jf][rf] = (f32x4){0.f, 0.f, 0.f, 0.f};

#pragma unroll
  for (int rf = 0; rf < 4; ++rf) {
    half8 b = {0, 0, 0, 0, 0, 0, 0, 0};
    if (lg == 0) {
      const float* xp = x + (size_t)(r0g + rf * 16 + lr) * 3;
      b[0] = (_Float16)xp[0];
      b[1] = (_Float16)xp[1];
      b[2] = (_Float16)xp[2];
    }
#pragma unroll
    for (int jf = 0; jf < 4; ++jf)
      acc[jf][rf] = __builtin_amdgcn_mfma_f32_16x16x32_f16(a[jf], b, acc[jf][rf], 0, 0, 0);
  }

#pragma unroll
  for (int jf = 0; jf < 4; ++jf) {
    f32x4 bj = *(const f32x4*)(b0 + j0 + jf * 16 + lg * 4);
#pragma unroll
    for (int rf = 0; rf < 4; ++rf) {
      f32x4 v = acc[jf][rf] + bj;
      half4 h;
#pragma unroll
      for (int u = 0; u < 4; ++u)
        h[u] = (_Float16)fmaxf(v[u], 0.f);
      *(half4*)(act + swz(rf * 16 + lr, j0 + jf * 16 + lg * 4)) = h;
    }
  }
  __syncthreads();
}

// ---------------------------------------------------------------------------
// Trunk: seg_sum(c) = tw2^T (sum_r a_r) + cnt*tb2 (tw2 layer has NO relu and
// feeds only the segment sum -> apply it per-SEGMENT, not per-node).
// Trunk kernel therefore only computes a = relu(tw1 ...) and seg-sums a.
// ---------------------------------------------------------------------------
__global__ __launch_bounds__(THREADS, 2)
void trunk_kernel(const float* __restrict__ nodes, const int* __restrict__ coord_seg,
                  const float* __restrict__ tw0, const float* __restrict__ tb0,
                  const char* __restrict__ wt3_1, const float* __restrict__ tb1,
                  float* __restrict__ seg_a)
{
  __shared__ __align__(16) char act[ROWS * HH * 2];   // 32KB
  __shared__ __align__(16) char wpan[4 * 12288];      // 48KB
  const int tid = threadIdx.x;
  const int r0g = blockIdx.x * ROWS;

  layer1_mfma(act, nodes, r0g, tw0, tb0, tid);
  heavy_layer<0>(act, wpan, wt3_1, tb1, nullptr, nullptr, tid);  // a

  {
    const int j = tid;
    const int s_lo = coord_seg[r0g];
    const int s_hi = coord_seg[r0g + ROWS - 1];
    if (s_lo == s_hi) {
      float p = 0.f;
#pragma unroll 8
      for (int r = 0; r < ROWS; ++r)
        p += (float)*(const _Float16*)(act + swz(r, j));
      atomicAdd(&seg_a[s_lo * HH + j], p);
    } else {
      for (int s = s_lo; s <= s_hi; ++s) {
        float p = 0.f;
        for (int r = 0; r < ROWS; ++r)
          if (coord_seg[r0g + r] == s)
            p += (float)*(const _Float16*)(act + swz(r, j));
        atomicAdd(&seg_a[s * HH + j], p);
      }
    }
  }
}

// seg_mean[s][j] = (sum_i seg_a[s][i]*tw2[i][j] + cnt_s*tb2[j]) / cnt_s
__global__ void segmix_kernel(const float* __restrict__ seg_a,
                              const int* __restrict__ coord_seg,
                              const float* __restrict__ tw2,
                              const float* __restrict__ tb2,
                              float* __restrict__ seg_mean)
{
  const int s = blockIdx.x, j = threadIdx.x;
  int lo = 0, n = NTOT;
  while (n > 0) { int h = n >> 1; int mid = lo + h;
    if (coord_seg[mid] < s) { lo = mid + 1; n -= h + 1; } else n = h; }
  int hi = lo; n = NTOT - lo;
  while (n > 0) { int h = n >> 1; int mid = hi + h;
    if (coord_seg[mid] < s + 1) { hi = mid + 1; n -= h + 1; } else n = h; }
  const float cnt = (float)(hi - lo);
  float acc = cnt * tb2[j];
  for (int i = 0; i < HH; ++i)
    acc = fmaf(seg_a[s * HH + i], tw2[i * HH + j], acc);
  seg_mean[s * HH + j] = acc / fmaxf(cnt, 1.0f);
}

// d_s[s][j] = ob0[j] + sum_i bb2[i] * m_s[i] * ow0[i][j]
__global__ void dbias_kernel(const float* __restrict__ seg_mean,
                             const float* __restrict__ bb2,
                             const float* __restrict__ ow0,
                             const float* __restrict__ ob0,
                             float* __restrict__ d_s)
{
  const int s = blockIdx.x, j = threadIdx.x;
  float acc = ob0[j];
  for (int i = 0; i < HH; ++i)
    acc = fmaf(bb2[i] * seg_mean[s * HH + i], ow0[i * HH + j], acc);
  d_s[s * HH + j] = acc;
}

// C_s[j][k] = sum_i bw2[k][i]*m_s[i]*ow0[i][j], written DIRECTLY in WT3
// slab-linear layout (so branch can DMA it like any other weight).
__global__ __launch_bounds__(THREADS, 2)
void cfuse_kernel(const float* __restrict__ bw2, const float* __restrict__ seg_mean,
                  const char* __restrict__ wt3_ow0, char* __restrict__ Cbuf)
{
  __shared__ __align__(16) char act[ROWS * HH * 2];
  __shared__ __align__(16) char wpan[4 * 12288];
  const int tid = threadIdx.x;
  const int s  = blockIdx.x >> 2;
  const int kc = blockIdx.x & 3;
  const int k0 = kc * 64;

  // Phase A: act[r'][i] = fp16(bw2[k0+r'][i] * m_s[i])
  {
    const int i = tid;
    const float mi = seg_mean[s * HH + i];
    for (int r = 0; r < ROWS; ++r)
      *(_Float16*)(act + swz(r, i)) = (_Float16)(bw2[(size_t)(k0 + r) * HH + i] * mi);
  }
  __syncthreads();

  const int wid  = tid >> 6;
  const int lane = tid & 63;
  const int lr   = lane & 15;
  const int lg   = lane >> 4;
  const int j0   = wid << 6;
  char* slab = wpan + wid * 12288;
  const char* wsrc = wt3_ow0 + wid * 4096;

  f32x4 acc[4][4];
#pragma unroll
  for (int jf = 0; jf < 4; ++jf)
#pragma unroll
    for (int rf = 0; rf < 4; ++rf)
      acc[jf][rf] = (f32x4){0.f, 0.f, 0.f, 0.f};

  stage_slab(wsrc + 0 * 16384, slab + 0 * 4096, lane);
  stage_slab(wsrc + 1 * 16384, slab + 1 * 4096, lane);
  stage_slab(wsrc + 2 * 16384, slab + 2 * 4096, lane);

  half8 a[2][4], b[2][4];
  asm volatile("s_waitcnt vmcnt(8)" ::: "memory");
  __builtin_amdgcn_sched_barrier(0);
#pragma unroll
  for (int rf = 0; rf < 4; ++rf)
    b[0][rf] = *(const half8*)(act + swz(rf * 16 + lr, 0 * 32 + lg * 8));
#pragma unroll
  for (int jf = 0; jf < 4; ++jf)
    a[0][jf] = *(const half8*)(slab + 0 * 4096 + jf * 1024 + lane * 16);

#pragma unroll
  for (int ks = 0; ks < 8; ++ks) {
    const int p = ks & 1;
    if (ks < 7) {
      if (ks < 6) asm volatile("s_waitcnt vmcnt(4)" ::: "memory");
      else        asm volatile("s_waitcnt vmcnt(0)" ::: "memory");
      __builtin_amdgcn_sched_barrier(0);
#pragma unroll
      for (int rf = 0; rf < 4; ++rf)
        b[p ^ 1][rf] = *(const half8*)(act + swz(rf * 16 + lr, (ks + 1) * 32 + lg * 8));
#pragma unroll
      for (int jf = 0; jf < 4; ++jf)
        a[p ^ 1][jf] = *(const half8*)(slab + ((ks + 1) % 3) * 4096 + jf * 1024 + lane * 16);
    }
    __builtin_amdgcn_sched_barrier(0);
#pragma unroll
    for (int jf = 0; jf < 4; ++jf)
#pragma unroll
      for (int rf = 0; rf < 4; ++rf)
        acc[jf][rf] = __builtin_amdgcn_mfma_f32_16x16x32_f16(a[p][jf], b[p][rf], acc[jf][rf], 0, 0, 0);
    __builtin_amdgcn_sched_barrier(0);
    if (ks < 5)
      stage_slab(wsrc + (ks + 3) * 16384, slab + (ks % 3) * 4096, lane);
  }
  // all DMAs retired -> wpan reusable as dbuf.

  // Phase C: dbuf[j][k'] fp16, row stride 128B, byte = j*128 + (k'*2 ^ ((j&7)<<4))
  char* dbuf = wpan;
#pragma unroll
  for (int jf = 0; jf < 4; ++jf)
#pragma unroll
    for (int rf = 0; rf < 4; ++rf) {
      const int kl = rf * 16 + lr;
#pragma unroll
      for (int u = 0; u < 4; ++u) {
        const int j = j0 + jf * 16 + lg * 4 + u;
        *(_Float16*)(dbuf + j * 128 + ((kl * 2) ^ ((j & 7) << 4))) = (_Float16)acc[jf][rf][u];
      }
    }
  __syncthreads();

  // Phase D: coalesced copy-out in slab-linear order.
  char* Cdst = Cbuf + (size_t)s * 131072 + (size_t)(kc * 2) * 16384;
#pragma unroll
  for (int c = 0; c < 8; ++c) {
    const uint32_t g = c * 4096 + tid * 16;
    const uint32_t sl = g >> 14;
    const uint32_t aa = g & 16383;
    const uint32_t wq = aa >> 12;
    const uint32_t jjf = (aa >> 10) & 3;
    const uint32_t l  = (aa >> 4) & 63;
    const uint32_t j  = wq * 64 + jjf * 16 + (l & 15);
    const uint32_t kl = sl * 32 + ((l >> 4) << 3);
    uint4 v = *(const uint4*)(dbuf + j * 128 + ((kl * 2) ^ ((j & 7) << 4)));
    *(uint4*)(Cdst + sl * 16384 + aa) = v;
  }
}

__global__ __launch_bounds__(THREADS, 2)
void branch_kernel(const float* __restrict__ known_nodes, const int* __restrict__ known_seg,
                   const float* __restrict__ bw0, const float* __restrict__ bb0,
                   const char* __restrict__ wt3_1, const float* __restrict__ bb1,
                   const char* __restrict__ wt3_2, const float* __restrict__ bb2,
                   const float* __restrict__ seg_mean,
                   const char* __restrict__ wt3_o, const float* __restrict__ ob0,
                   const float* __restrict__ ow1, const float* __restrict__ ob1,
                   const char* __restrict__ Cbuf, const float* __restrict__ d_s,
                   int use_fuse, float* __restrict__ out)
{
  __shared__ __align__(16) char act[ROWS * HH * 2];
  __shared__ __align__(16) char wpan[4 * 12288];
  const int tid = threadIdx.x;
  // XCD-aware bijective swizzle (4096 % 8 == 0): same-segment blocks share an
  // XCD -> each L2 caches only its ~1MB slice of Cbuf.
  const int bid = ((int)blockIdx.x & 7) * ((int)gridDim.x >> 3) + ((int)blockIdx.x >> 3);
  const int r0g = bid * ROWS;

  layer1_mfma(act, known_nodes, r0g, bw0, bb0, tid);
  heavy_layer<0>(act, wpan, wt3_1, bb1, nullptr, nullptr, tid);

  const int s_lo = known_seg[r0g];
  const int s_hi = known_seg[r0g + ROWS - 1];
  if (use_fuse && s_lo == s_hi) {
    heavy_layer<0>(act, wpan, Cbuf + (size_t)s_lo * 131072, d_s + s_lo * HH,
                   nullptr, nullptr, tid);
  } else {
    heavy_layer<2>(act, wpan, wt3_2, bb2, seg_mean, known_seg + r0g, tid);
    heavy_layer<0>(act, wpan, wt3_o, ob0, nullptr, nullptr, tid);
  }

  // out = h @ ow1 + ob1 (256 -> 3): 256 threads, 4 k-quarters in parallel.
  float* ps = (float*)wpan;
  {
    const int r = tid & 63;
    const int q = tid >> 6;
    float o0 = 0.f, o1 = 0.f, o2 = 0.f;
    for (int kk = 0; kk < 64; kk += 8) {
      int k0 = q * 64 + kk;
      half8 h = *(const half8*)(act + swz(r, k0));
#pragma unroll
      for (int u = 0; u < 8; ++u) {
        float a = (float)h[u];
        o0 = fmaf(a, ow1[(k0 + u) * 3 + 0], o0);
        o1 = fmaf(a, ow1[(k0 + u) * 3 + 1], o1);
        o2 = fmaf(a, ow1[(k0 + u) * 3 + 2], o2);
      }
    }
    float* p = ps + q * ROWS * 3;
    p[r * 3 + 0] = o0; p[r * 3 + 1] = o1; p[r * 3 + 2] = o2;
  }
  __syncthreads();
  if (tid < ROWS) {
    const int r = tid;
    float* dst = out + (size_t)(r0g + r) * 3;
#pragma unroll
    for (int c = 0; c < 3; ++c) {
      float o = ob1[c];
#pragma unroll
      for (int q = 0; q < 4; ++q) o += ps[q * ROWS * 3 + r * 3 + c];
      dst[c] = o;
    }
  }
}

// W[256][256] fp32 (row=k, col=j) -> WT3 slab-linear fp16 (4 matrices).
struct WPtrs { const float* w[4]; char* wt3[4]; };
__global__ void transpose_kernel(WPtrs p)
{
  const int m = blockIdx.x >> 8;
  const int k = blockIdx.x & 255;
  const int j = threadIdx.x;
  size_t off = (size_t)(k >> 5) * 16384 + (size_t)(j >> 6) * 4096
             + (size_t)((j >> 4) & 3) * 1024
             + (size_t)((((k >> 3) & 3) << 4) | (j & 15)) * 16
             + (size_t)(k & 7) * 2;
  *(_Float16*)(p.wt3[m] + off) = (_Float16)p.w[m][k * HH + j];
}

__global__ void zero_kernel(float* __restrict__ p, int n)
{
  int i = blockIdx.x * blockDim.x + threadIdx.x;
  if (i < n) p[i] = 0.f;
}

// ---------------------------------------------------------------------------
extern "C" void kernel_launch(void* const* d_in, const int* in_sizes, int n_in,
                              void* d_out, int out_size, void* d_ws, size_t ws_size,
                              hipStream_t stream)
{
  const float* known_nodes = (const float*)d_in[0];
  const float* nodes       = (const float*)d_in[1];
  const int*   known_seg   = (const int*)d_in[2];
  const int*   coord_seg   = (const int*)d_in[3];
  const float* bw0 = (const float*)d_in[4];
  const float* bb0 = (const float*)d_in[5];
  const float* bw1 = (const float*)d_in[6];
  const float* bb1 = (const float*)d_in[7];
  const float* bw2 = (const float*)d_in[8];
  const float* bb2 = (const float*)d_in[9];
  const float* tw0 = (const float*)d_in[10];
  const float* tb0 = (const float*)d_in[11];
  const float* tw1 = (const float*)d_in[12];
  const float* tb1 = (const float*)d_in[13];
  const float* tw2 = (const float*)d_in[14];
  const float* tb2 = (const float*)d_in[15];
  const float* ow0 = (const float*)d_in[16];
  const float* ob0 = (const float*)d_in[17];
  const float* ow1 = (const float*)d_in[18];
  const float* ob1 = (const float*)d_in[19];

  float* out      = (float*)d_out;
  char* p = (char*)d_ws;
  float* seg_a    = (float*)p;            p += (size_t)NB * HH * 4;
  float* seg_mean = (float*)p;            p += (size_t)NB * HH * 4;
  char* wt3_tw1 = p;  p += (size_t)HH * HH * 2;
  char* wt3_bw1 = p;  p += (size_t)HH * HH * 2;
  char* wt3_bw2 = p;  p += (size_t)HH * HH * 2;
  char* wt3_ow0 = p;  p += (size_t)HH * HH * 2;
  float* d_s    = (float*)p;              p += (size_t)NB * HH * 4;
  char* Cbuf    = p;                      p += (size_t)NB * HH * HH * 2;  // 8MB
  const int use_fuse = ((size_t)(p - (char*)d_ws) <= ws_size) ? 1 : 0;

  WPtrs wp;
  wp.w[0] = tw1; wp.wt3[0] = wt3_tw1;
  wp.w[1] = bw1; wp.wt3[1] = wt3_bw1;
  wp.w[2] = bw2; wp.wt3[2] = wt3_bw2;
  wp.w[3] = ow0; wp.wt3[3] = wt3_ow0;

  transpose_kernel<<<4 * 256, 256, 0, stream>>>(wp);
  zero_kernel<<<(NB * HH + 255) / 256, 256, 0, stream>>>(seg_a, NB * HH);
  trunk_kernel<<<NTOT / ROWS, THREADS, 0, stream>>>(nodes, coord_seg,
                                                    tw0, tb0, wt3_tw1, tb1,
                                                    seg_a);
  segmix_kernel<<<NB, 256, 0, stream>>>(seg_a, coord_seg, tw2, tb2, seg_mean);
  if (use_fuse) {
    dbias_kernel<<<NB, 256, 0, stream>>>(seg_mean, bb2, ow0, ob0, d_s);
    cfuse_kernel<<<NB * 4, THREADS, 0, stream>>>(bw2, seg_mean, wt3_ow0, Cbuf);
  }
  branch_kernel<<<NTOT / ROWS, THREADS, 0, stream>>>(known_nodes, known_seg,
                                                     bw0, bb0, wt3_bw1, bb1, wt3_bw2, bb2,
                                                     seg_mean,
                                                     wt3_ow0, ob0, ow1, ob1,
                                                     Cbuf, d_s, use_fuse,
                                                     out);
}

// Round 24
// 202.085 us; speedup vs baseline: 1.4073x; 1.1026x over previous
//
#include <hip/hip_runtime.h>

#define HH 256       // hidden size
#define NB 64        // batch (segments)
#define ROWS 64      // rows per block tile
#define NTOT 262144  // NK == NC
#define THREADS 256  // 4 waves

typedef _Float16 half8 __attribute__((ext_vector_type(8)));
typedef _Float16 half4 __attribute__((ext_vector_type(4)));
typedef float f32x4 __attribute__((ext_vector_type(4)));

typedef __attribute__((address_space(1))) const void gas_t;
typedef __attribute__((address_space(3))) void las_t;

// act LDS tile: [row][k] fp16, 64 rows x 256 k = 32KB, row stride 512B.
__device__ __forceinline__ uint32_t swz(uint32_t r, uint32_t k) {
  return (((r << 9) + (k << 1)) ^ ((r & 7) << 4)) ^ ((r & 8) << 3);
}

// Stage one wave-private 4KB A-slab (64 j x 32 k): 4 DMA calls x 1KB.
__device__ __forceinline__ void stage_slab(const char* __restrict__ g, char* l,
                                           int lane)
{
  const char* gp = g + lane * 16;
#pragma unroll
  for (int c = 0; c < 4; ++c)
    __builtin_amdgcn_global_load_lds((gas_t*)(gp + c * 1024), (las_t*)(l + c * 1024),
                                     16, 0, 0);
}

// Shared MFMA body for the R17 heavy layer: acc += WT-slabs x act.
#define HEAVY_MFMA_BODY(act, slab, wsrc)                                        \
  f32x4 acc[4][4];                                                              \
  _Pragma("unroll")                                                             \
  for (int jf = 0; jf < 4; ++jf)                                                \
    _Pragma("unroll")                                                           \
    for (int rf = 0; rf < 4; ++rf)                                              \
      acc[jf][rf] = (f32x4){0.f, 0.f, 0.f, 0.f};                                \
  stage_slab(wsrc + 0 * 16384, slab + 0 * 4096, lane);                          \
  stage_slab(wsrc + 1 * 16384, slab + 1 * 4096, lane);                          \
  stage_slab(wsrc + 2 * 16384, slab + 2 * 4096, lane);                          \
  half8 a[2][4], b[2][4];                                                       \
  asm volatile("s_waitcnt vmcnt(8)" ::: "memory");                              \
  __builtin_amdgcn_sched_barrier(0);                                            \
  _Pragma("unroll")                                                             \
  for (int rf = 0; rf < 4; ++rf)                                                \
    b[0][rf] = *(const half8*)(act + swz(rf * 16 + lr, 0 * 32 + lg * 8));       \
  _Pragma("unroll")                                                             \
  for (int jf = 0; jf < 4; ++jf)                                                \
    a[0][jf] = *(const half8*)(slab + 0 * 4096 + jf * 1024 + lane * 16);        \
  _Pragma("unroll")                                                             \
  for (int ks = 0; ks < 8; ++ks) {                                              \
    const int p = ks & 1;                                                       \
    if (ks < 7) {                                                               \
      if (ks < 6) asm volatile("s_waitcnt vmcnt(4)" ::: "memory");              \
      else        asm volatile("s_waitcnt vmcnt(0)" ::: "memory");              \
      __builtin_amdgcn_sched_barrier(0);                                        \
      _Pragma("unroll")                                                         \
      for (int rf = 0; rf < 4; ++rf)                                            \
        b[p ^ 1][rf] = *(const half8*)(act + swz(rf * 16 + lr, (ks + 1) * 32 + lg * 8)); \
      _Pragma("unroll")                                                         \
      for (int jf = 0; jf < 4; ++jf)                                            \
        a[p ^ 1][jf] = *(const half8*)(slab + ((ks + 1) % 3) * 4096 + jf * 1024 + lane * 16); \
    }                                                                           \
    __builtin_amdgcn_sched_barrier(0);                                          \
    _Pragma("unroll")                                                           \
    for (int jf = 0; jf < 4; ++jf)                                              \
      _Pragma("unroll")                                                         \
      for (int rf = 0; rf < 4; ++rf)                                            \
        acc[jf][rf] = __builtin_amdgcn_mfma_f32_16x16x32_f16(a[p][jf], b[p][rf], acc[jf][rf], 0, 0, 0); \
    __builtin_amdgcn_sched_barrier(0);                                          \
    if (ks < 5)                                                                 \
      stage_slab(wsrc + (ks + 3) * 16384, slab + (ks % 3) * 4096, lane);        \
  }

// ---------------------------------------------------------------------------
// R17 heavy layer. MODE: 0 relu; 2 multiply seg_mean[seg_g[r]] (mixed path)
// ---------------------------------------------------------------------------
template<int MODE>
__device__ __forceinline__ void heavy_layer(char* act, char* wpan,
                                            const char* __restrict__ wt3,
                                            const float* __restrict__ bias,
                                            const float* __restrict__ seg_mean,
                                            const int* __restrict__ seg_g, int tid)
{
  const int wid  = tid >> 6;
  const int lane = tid & 63;
  const int lr   = lane & 15;
  const int lg   = lane >> 4;
  const int j0   = wid << 6;
  char* slab = wpan + wid * 12288;
  const char* wsrc = wt3 + wid * 4096;

  HEAVY_MFMA_BODY(act, slab, wsrc)

  int sseg[4];
  if (MODE == 2) {
#pragma unroll
    for (int rf = 0; rf < 4; ++rf) sseg[rf] = seg_g[rf * 16 + lr];
  }

  __syncthreads();  // all waves done READING act before overwrite

#pragma unroll
  for (int jf = 0; jf < 4; ++jf) {
    f32x4 bj = *(const f32x4*)(bias + j0 + jf * 16 + lg * 4);
#pragma unroll
    for (int rf = 0; rf < 4; ++rf) {
      f32x4 v = acc[jf][rf] + bj;
      if (MODE == 2) {
        f32x4 sm = *(const f32x4*)(seg_mean + sseg[rf] * HH + j0 + jf * 16 + lg * 4);
        v *= sm;
      }
      half4 h;
#pragma unroll
      for (int u = 0; u < 4; ++u) {
        float x = v[u];
        if (MODE == 0) x = fmaxf(x, 0.f);
        h[u] = (_Float16)x;
      }
      *(half4*)(act + swz(rf * 16 + lr, j0 + jf * 16 + lg * 4)) = h;
    }
  }
  __syncthreads();
}

// ---------------------------------------------------------------------------
// Last branch layer with FUSED OUTPUT: out = relu(W a + bias) @ ow1 + ob1.
// h never touches LDS: lane applies bias+relu to its accs and dots with its
// 16 ow1 rows; shfl-reduce over the 4 lg-lanes sharing r; ps holds per-wave
// partials. Deletes 32KB act write + 32KB tail read + 1 barrier.
// ---------------------------------------------------------------------------
__device__ __forceinline__ void heavy_layer_out(char* act, char* wpan,
                                                const char* __restrict__ wt3,
                                                const float* __restrict__ bias,
                                                const float* __restrict__ ow1,
                                                const float* __restrict__ ob1,
                                                float* __restrict__ out,
                                                int r0g, int tid)
{
  const int wid  = tid >> 6;
  const int lane = tid & 63;
  const int lr   = lane & 15;
  const int lg   = lane >> 4;
  const int j0   = wid << 6;
  char* slab = wpan + wid * 12288;
  const char* wsrc = wt3 + wid * 4096;

  HEAVY_MFMA_BODY(act, slab, wsrc)

  float o[4][3];
#pragma unroll
  for (int rf = 0; rf < 4; ++rf)
#pragma unroll
    for (int c = 0; c < 3; ++c) o[rf][c] = 0.f;

#pragma unroll
  for (int jf = 0; jf < 4; ++jf) {
    f32x4 bj = *(const f32x4*)(bias + j0 + jf * 16 + lg * 4);
#pragma unroll
    for (int u = 0; u < 4; ++u) {
      const int j = j0 + jf * 16 + lg * 4 + u;
      const float w0 = ow1[j * 3 + 0], w1 = ow1[j * 3 + 1], w2 = ow1[j * 3 + 2];
#pragma unroll
      for (int rf = 0; rf < 4; ++rf) {
        float x = fmaxf(acc[jf][rf][u] + bj[u], 0.f);
        o[rf][0] = fmaf(x, w0, o[rf][0]);
        o[rf][1] = fmaf(x, w1, o[rf][1]);
        o[rf][2] = fmaf(x, w2, o[rf][2]);
      }
    }
  }

  // reduce over the 4 lg-lanes that share r (lane ^ 16, ^ 32)
#pragma unroll
  for (int rf = 0; rf < 4; ++rf)
#pragma unroll
    for (int c = 0; c < 3; ++c) {
      o[rf][c] += __shfl_xor(o[rf][c], 16);
      o[rf][c] += __shfl_xor(o[rf][c], 32);
    }

  __syncthreads();  // all waves done with their wpan slabs (ps aliases wpan)
  float* ps = (float*)wpan;  // [4 wid][64 r][3]
  if (lg == 0) {
#pragma unroll
    for (int rf = 0; rf < 4; ++rf) {
      const int r = rf * 16 + lr;
#pragma unroll
      for (int c = 0; c < 3; ++c) ps[wid * 192 + r * 3 + c] = o[rf][c];
    }
  }
  __syncthreads();
  if (tid < ROWS) {
    const int r = tid;
    float* dst = out + (size_t)(r0g + r) * 3;
#pragma unroll
    for (int c = 0; c < 3; ++c) {
      float v = ob1[c];
#pragma unroll
      for (int w = 0; w < 4; ++w) v += ps[w * 192 + r * 3 + c];
      dst[c] = v;
    }
  }
}

// layer 1 via MFMA: F=3 -> H (relu), K padded 3 -> 32 with zeros.
__device__ __forceinline__ void layer1_mfma(char* act, const float* __restrict__ x,
                                            int r0g, const float* __restrict__ W0,
                                            const float* __restrict__ b0, int tid)
{
  const int wid  = tid >> 6;
  const int lane = tid & 63;
  const int lr   = lane & 15;
  const int lg   = lane >> 4;
  const int j0   = wid << 6;

  half8 a[4];
#pragma unroll
  for (int jf = 0; jf < 4; ++jf) {
    half8 v = {0, 0, 0, 0, 0, 0, 0, 0};
    if (lg == 0) {
      int j = j0 + jf * 16 + lr;
      v[0] = (_Float16)W0[j];
      v[1] = (_Float16)W0[HH + j];
      v[2] = (_Float16)W0[2 * HH + j];
    }
    a[jf] = v;
  }

  f32x4 acc[4][4];
#pragma unroll
  for (int jf = 0; jf < 4; ++jf)
#pragma unroll
    for (int rf = 0; rf < 4; ++rf)
      acc[jf][rf] = (f32x4){0.f, 0.f, 0.f, 0.f};

#pragma unroll
  for (int rf = 0; rf < 4; ++rf) {
    half8 b = {0, 0, 0, 0, 0, 0, 0, 0};
    if (lg == 0) {
      const float* xp = x + (size_t)(r0g + rf * 16 + lr) * 3;
      b[0] = (_Float16)xp[0];
      b[1] = (_Float16)xp[1];
      b[2] = (_Float16)xp[2];
    }
#pragma unroll
    for (int jf = 0; jf < 4; ++jf)
      acc[jf][rf] = __builtin_amdgcn_mfma_f32_16x16x32_f16(a[jf], b, acc[jf][rf], 0, 0, 0);
  }

#pragma unroll
  for (int jf = 0; jf < 4; ++jf) {
    f32x4 bj = *(const f32x4*)(b0 + j0 + jf * 16 + lg * 4);
#pragma unroll
    for (int rf = 0; rf < 4; ++rf) {
      f32x4 v = acc[jf][rf] + bj;
      half4 h;
#pragma unroll
      for (int u = 0; u < 4; ++u)
        h[u] = (_Float16)fmaxf(v[u], 0.f);
      *(half4*)(act + swz(rf * 16 + lr, j0 + jf * 16 + lg * 4)) = h;
    }
  }
  __syncthreads();
}

// ---------------------------------------------------------------------------
// Trunk: only a = relu(layer2) is needed per node; tw2 applied per-segment.
// ---------------------------------------------------------------------------
__global__ __launch_bounds__(THREADS, 2)
void trunk_kernel(const float* __restrict__ nodes, const int* __restrict__ coord_seg,
                  const float* __restrict__ tw0, const float* __restrict__ tb0,
                  const char* __restrict__ wt3_1, const float* __restrict__ tb1,
                  float* __restrict__ seg_a)
{
  __shared__ __align__(16) char act[ROWS * HH * 2];   // 32KB
  __shared__ __align__(16) char wpan[4 * 12288];      // 48KB
  const int tid = threadIdx.x;
  const int r0g = blockIdx.x * ROWS;

  layer1_mfma(act, nodes, r0g, tw0, tb0, tid);
  heavy_layer<0>(act, wpan, wt3_1, tb1, nullptr, nullptr, tid);  // a

  {
    const int j = tid;
    const int s_lo = coord_seg[r0g];
    const int s_hi = coord_seg[r0g + ROWS - 1];
    if (s_lo == s_hi) {
      float p = 0.f;
#pragma unroll 8
      for (int r = 0; r < ROWS; ++r)
        p += (float)*(const _Float16*)(act + swz(r, j));
      atomicAdd(&seg_a[s_lo * HH + j], p);
    } else {
      for (int s = s_lo; s <= s_hi; ++s) {
        float p = 0.f;
        for (int r = 0; r < ROWS; ++r)
          if (coord_seg[r0g + r] == s)
            p += (float)*(const _Float16*)(act + swz(r, j));
        atomicAdd(&seg_a[s * HH + j], p);
      }
    }
  }
}

// segprep: seg_mean then d_s (fused; seg_mean kept in LDS for phase 2).
__global__ void segprep_kernel(const float* __restrict__ seg_a,
                               const int* __restrict__ coord_seg,
                               const float* __restrict__ tw2,
                               const float* __restrict__ tb2,
                               const float* __restrict__ bb2,
                               const float* __restrict__ ow0,
                               const float* __restrict__ ob0,
                               float* __restrict__ seg_mean,
                               float* __restrict__ d_s)
{
  __shared__ float sm[HH];
  const int s = blockIdx.x, j = threadIdx.x;
  int lo = 0, n = NTOT;
  while (n > 0) { int h = n >> 1; int mid = lo + h;
    if (coord_seg[mid] < s) { lo = mid + 1; n -= h + 1; } else n = h; }
  int hi = lo; n = NTOT - lo;
  while (n > 0) { int h = n >> 1; int mid = hi + h;
    if (coord_seg[mid] < s + 1) { hi = mid + 1; n -= h + 1; } else n = h; }
  const float cnt = (float)(hi - lo);
  float acc = cnt * tb2[j];
  for (int i = 0; i < HH; ++i)
    acc = fmaf(seg_a[s * HH + i], tw2[i * HH + j], acc);
  acc /= fmaxf(cnt, 1.0f);
  seg_mean[s * HH + j] = acc;
  sm[j] = acc;
  __syncthreads();
  float d = ob0[j];
  for (int i = 0; i < HH; ++i)
    d = fmaf(bb2[i] * sm[i], ow0[i * HH + j], d);
  d_s[s * HH + j] = d;
}

// C_s[j][k] = sum_i bw2[k][i]*m_s[i]*ow0[i][j], written in WT3 slab layout.
__global__ __launch_bounds__(THREADS, 2)
void cfuse_kernel(const float* __restrict__ bw2, const float* __restrict__ seg_mean,
                  const char* __restrict__ wt3_ow0, char* __restrict__ Cbuf)
{
  __shared__ __align__(16) char act[ROWS * HH * 2];
  __shared__ __align__(16) char wpan[4 * 12288];
  const int tid = threadIdx.x;
  const int s  = blockIdx.x >> 2;
  const int kc = blockIdx.x & 3;
  const int k0 = kc * 64;

  {
    const int i = tid;
    const float mi = seg_mean[s * HH + i];
    for (int r = 0; r < ROWS; ++r)
      *(_Float16*)(act + swz(r, i)) = (_Float16)(bw2[(size_t)(k0 + r) * HH + i] * mi);
  }
  __syncthreads();

  const int wid  = tid >> 6;
  const int lane = tid & 63;
  const int lr   = lane & 15;
  const int lg   = lane >> 4;
  const int j0   = wid << 6;
  char* slab = wpan + wid * 12288;
  const char* wsrc = wt3_ow0 + wid * 4096;

  HEAVY_MFMA_BODY(act, slab, wsrc)

  // dbuf[j][k'] fp16, row 128B, byte = j*128 + (k'*2 ^ ((j&7)<<4))
  __syncthreads();
  char* dbuf = wpan;
#pragma unroll
  for (int jf = 0; jf < 4; ++jf)
#pragma unroll
    for (int rf = 0; rf < 4; ++rf) {
      const int kl = rf * 16 + lr;
#pragma unroll
      for (int u = 0; u < 4; ++u) {
        const int j = j0 + jf * 16 + lg * 4 + u;
        *(_Float16*)(dbuf + j * 128 + ((kl * 2) ^ ((j & 7) << 4))) = (_Float16)acc[jf][rf][u];
      }
    }
  __syncthreads();

  char* Cdst = Cbuf + (size_t)s * 131072 + (size_t)(kc * 2) * 16384;
#pragma unroll
  for (int c = 0; c < 8; ++c) {
    const uint32_t g = c * 4096 + tid * 16;
    const uint32_t sl = g >> 14;
    const uint32_t aa = g & 16383;
    const uint32_t wq = aa >> 12;
    const uint32_t jjf = (aa >> 10) & 3;
    const uint32_t l  = (aa >> 4) & 63;
    const uint32_t j  = wq * 64 + jjf * 16 + (l & 15);
    const uint32_t kl = sl * 32 + ((l >> 4) << 3);
    uint4 v = *(const uint4*)(dbuf + j * 128 + ((kl * 2) ^ ((j & 7) << 4)));
    *(uint4*)(Cdst + sl * 16384 + aa) = v;
  }
}

__global__ __launch_bounds__(THREADS, 2)
void branch_kernel(const float* __restrict__ known_nodes, const int* __restrict__ known_seg,
                   const float* __restrict__ bw0, const float* __restrict__ bb0,
                   const char* __restrict__ wt3_1, const float* __restrict__ bb1,
                   const char* __restrict__ wt3_2, const float* __restrict__ bb2,
                   const float* __restrict__ seg_mean,
                   const char* __restrict__ wt3_o, const float* __restrict__ ob0,
                   const float* __restrict__ ow1, const float* __restrict__ ob1,
                   const char* __restrict__ Cbuf, const float* __restrict__ d_s,
                   int use_fuse, float* __restrict__ out)
{
  __shared__ __align__(16) char act[ROWS * HH * 2];
  __shared__ __align__(16) char wpan[4 * 12288];
  const int tid = threadIdx.x;
  // XCD-aware bijective swizzle: same-segment blocks share an XCD.
  const int bid = ((int)blockIdx.x & 7) * ((int)gridDim.x >> 3) + ((int)blockIdx.x >> 3);
  const int r0g = bid * ROWS;

  layer1_mfma(act, known_nodes, r0g, bw0, bb0, tid);
  heavy_layer<0>(act, wpan, wt3_1, bb1, nullptr, nullptr, tid);

  const int s_lo = known_seg[r0g];
  const int s_hi = known_seg[r0g + ROWS - 1];
  if (use_fuse && s_lo == s_hi) {
    heavy_layer_out(act, wpan, Cbuf + (size_t)s_lo * 131072, d_s + s_lo * HH,
                    ow1, ob1, out, r0g, tid);
  } else {
    heavy_layer<2>(act, wpan, wt3_2, bb2, seg_mean, known_seg + r0g, tid);
    heavy_layer_out(act, wpan, wt3_o, ob0, ow1, ob1, out, r0g, tid);
  }
}

// W fp32 (row=k,col=j) -> WT3 slab-linear fp16 (4 matrices) + seg_a zeroing.
struct WPtrs { const float* w[4]; char* wt3[4]; };
__global__ void transpose_kernel(WPtrs p, float* __restrict__ seg_a)
{
  const int m = blockIdx.x >> 8;
  const int k = blockIdx.x & 255;
  const int j = threadIdx.x;
  if (blockIdx.x < 16) {
    float4 z = {0.f, 0.f, 0.f, 0.f};
    *(float4*)(seg_a + (size_t)blockIdx.x * 1024 + j * 4) = z;
  }
  size_t off = (size_t)(k >> 5) * 16384 + (size_t)(j >> 6) * 4096
             + (size_t)((j >> 4) & 3) * 1024
             + (size_t)((((k >> 3) & 3) << 4) | (j & 15)) * 16
             + (size_t)(k & 7) * 2;
  *(_Float16*)(p.wt3[m] + off) = (_Float16)p.w[m][k * HH + j];
}

// ---------------------------------------------------------------------------
extern "C" void kernel_launch(void* const* d_in, const int* in_sizes, int n_in,
                              void* d_out, int out_size, void* d_ws, size_t ws_size,
                              hipStream_t stream)
{
  const float* known_nodes = (const float*)d_in[0];
  const float* nodes       = (const float*)d_in[1];
  const int*   known_seg   = (const int*)d_in[2];
  const int*   coord_seg   = (const int*)d_in[3];
  const float* bw0 = (const float*)d_in[4];
  const float* bb0 = (const float*)d_in[5];
  const float* bw1 = (const float*)d_in[6];
  const float* bb1 = (const float*)d_in[7];
  const float* bw2 = (const float*)d_in[8];
  const float* bb2 = (const float*)d_in[9];
  const float* tw0 = (const float*)d_in[10];
  const float* tb0 = (const float*)d_in[11];
  const float* tw1 = (const float*)d_in[12];
  const float* tb1 = (const float*)d_in[13];
  const float* tw2 = (const float*)d_in[14];
  const float* tb2 = (const float*)d_in[15];
  const float* ow0 = (const float*)d_in[16];
  const float* ob0 = (const float*)d_in[17];
  const float* ow1 = (const float*)d_in[18];
  const float* ob1 = (const float*)d_in[19];

  float* out      = (float*)d_out;
  char* p = (char*)d_ws;
  float* seg_a    = (float*)p;            p += (size_t)NB * HH * 4;
  float* seg_mean = (float*)p;            p += (size_t)NB * HH * 4;
  char* wt3_tw1 = p;  p += (size_t)HH * HH * 2;
  char* wt3_bw1 = p;  p += (size_t)HH * HH * 2;
  char* wt3_bw2 = p;  p += (size_t)HH * HH * 2;
  char* wt3_ow0 = p;  p += (size_t)HH * HH * 2;
  float* d_s    = (float*)p;              p += (size_t)NB * HH * 4;
  char* Cbuf    = p;                      p += (size_t)NB * HH * HH * 2;  // 8MB
  const int use_fuse = ((size_t)(p - (char*)d_ws) <= ws_size) ? 1 : 0;

  WPtrs wp;
  wp.w[0] = tw1; wp.wt3[0] = wt3_tw1;
  wp.w[1] = bw1; wp.wt3[1] = wt3_bw1;
  wp.w[2] = bw2; wp.wt3[2] = wt3_bw2;
  wp.w[3] = ow0; wp.wt3[3] = wt3_ow0;

  transpose_kernel<<<4 * 256, 256, 0, stream>>>(wp, seg_a);
  trunk_kernel<<<NTOT / ROWS, THREADS, 0, stream>>>(nodes, coord_seg,
                                                    tw0, tb0, wt3_tw1, tb1,
                                                    seg_a);
  segprep_kernel<<<NB, 256, 0, stream>>>(seg_a, coord_seg, tw2, tb2,
                                         bb2, ow0, ob0, seg_mean, d_s);
  if (use_fuse)
    cfuse_kernel<<<NB * 4, THREADS, 0, stream>>>(bw2, seg_mean, wt3_ow0, Cbuf);
  branch_kernel<<<NTOT / ROWS, THREADS, 0, stream>>>(known_nodes, known_seg,
                                                     bw0, bb0, wt3_bw1, bb1, wt3_bw2, bb2,
                                                     seg_mean,
                                                     wt3_ow0, ob0, ow1, ob1,
                                                     Cbuf, d_s, use_fuse,
                                                     out);
}

// Round 25
// 196.612 us; speedup vs baseline: 1.4465x; 1.0278x over previous
//
#include <hip/hip_runtime.h>

#define HH 256       // hidden size
#define NB 64        // batch (segments)
#define ROWS 64      // rows per block tile
#define NTOT 262144  // NK == NC
#define THREADS 256  // 4 waves

typedef _Float16 half8 __attribute__((ext_vector_type(8)));
typedef _Float16 half4 __attribute__((ext_vector_type(4)));
typedef float f32x4 __attribute__((ext_vector_type(4)));

typedef __attribute__((address_space(1))) const void gas_t;
typedef __attribute__((address_space(3))) void las_t;

// act LDS tile: [row][k] fp16, 64 rows x 256 k = 32KB, row stride 512B.
__device__ __forceinline__ uint32_t swz(uint32_t r, uint32_t k) {
  return (((r << 9) + (k << 1)) ^ ((r & 7) << 4)) ^ ((r & 8) << 3);
}

// Stage one wave-private 4KB A-slab (64 j x 32 k): 4 DMA calls x 1KB.
__device__ __forceinline__ void stage_slab(const char* __restrict__ g, char* l,
                                           int lane)
{
  const char* gp = g + lane * 16;
#pragma unroll
  for (int c = 0; c < 4; ++c)
    __builtin_amdgcn_global_load_lds((gas_t*)(gp + c * 1024), (las_t*)(l + c * 1024),
                                     16, 0, 0);
}

// Shared MFMA body for the R17 heavy layer: acc += WT-slabs x act.
#define HEAVY_MFMA_BODY(act, slab, wsrc)                                        \
  f32x4 acc[4][4];                                                              \
  _Pragma("unroll")                                                             \
  for (int jf = 0; jf < 4; ++jf)                                                \
    _Pragma("unroll")                                                           \
    for (int rf = 0; rf < 4; ++rf)                                              \
      acc[jf][rf] = (f32x4){0.f, 0.f, 0.f, 0.f};                                \
  stage_slab(wsrc + 0 * 16384, slab + 0 * 4096, lane);                          \
  stage_slab(wsrc + 1 * 16384, slab + 1 * 4096, lane);                          \
  stage_slab(wsrc + 2 * 16384, slab + 2 * 4096, lane);                          \
  half8 a[2][4], b[2][4];                                                       \
  asm volatile("s_waitcnt vmcnt(8)" ::: "memory");                              \
  __builtin_amdgcn_sched_barrier(0);                                            \
  _Pragma("unroll")                                                             \
  for (int rf = 0; rf < 4; ++rf)                                                \
    b[0][rf] = *(const half8*)(act + swz(rf * 16 + lr, 0 * 32 + lg * 8));       \
  _Pragma("unroll")                                                             \
  for (int jf = 0; jf < 4; ++jf)                                                \
    a[0][jf] = *(const half8*)(slab + 0 * 4096 + jf * 1024 + lane * 16);        \
  _Pragma("unroll")                                                             \
  for (int ks = 0; ks < 8; ++ks) {                                              \
    const int p = ks & 1;                                                       \
    if (ks < 7) {                                                               \
      if (ks < 6) asm volatile("s_waitcnt vmcnt(4)" ::: "memory");              \
      else        asm volatile("s_waitcnt vmcnt(0)" ::: "memory");              \
      __builtin_amdgcn_sched_barrier(0);                                        \
      _Pragma("unroll")                                                         \
      for (int rf = 0; rf < 4; ++rf)                                            \
        b[p ^ 1][rf] = *(const half8*)(act + swz(rf * 16 + lr, (ks + 1) * 32 + lg * 8)); \
      _Pragma("unroll")                                                         \
      for (int jf = 0; jf < 4; ++jf)                                            \
        a[p ^ 1][jf] = *(const half8*)(slab + ((ks + 1) % 3) * 4096 + jf * 1024 + lane * 16); \
    }                                                                           \
    __builtin_amdgcn_sched_barrier(0);                                          \
    _Pragma("unroll")                                                           \
    for (int jf = 0; jf < 4; ++jf)                                              \
      _Pragma("unroll")                                                         \
      for (int rf = 0; rf < 4; ++rf)                                            \
        acc[jf][rf] = __builtin_amdgcn_mfma_f32_16x16x32_f16(a[p][jf], b[p][rf], acc[jf][rf], 0, 0, 0); \
    __builtin_amdgcn_sched_barrier(0);                                          \
    if (ks < 5)                                                                 \
      stage_slab(wsrc + (ks + 3) * 16384, slab + (ks % 3) * 4096, lane);        \
  }

// ---------------------------------------------------------------------------
// R17 heavy layer. MODE: 0 relu; 2 multiply seg_mean[seg_g[r]] (mixed path)
// ---------------------------------------------------------------------------
template<int MODE>
__device__ __forceinline__ void heavy_layer(char* act, char* wpan,
                                            const char* __restrict__ wt3,
                                            const float* __restrict__ bias,
                                            const float* __restrict__ seg_mean,
                                            const int* __restrict__ seg_g, int tid)
{
  const int wid  = tid >> 6;
  const int lane = tid & 63;
  const int lr   = lane & 15;
  const int lg   = lane >> 4;
  const int j0   = wid << 6;
  char* slab = wpan + wid * 12288;
  const char* wsrc = wt3 + wid * 4096;

  HEAVY_MFMA_BODY(act, slab, wsrc)

  int sseg[4];
  if (MODE == 2) {
#pragma unroll
    for (int rf = 0; rf < 4; ++rf) sseg[rf] = seg_g[rf * 16 + lr];
  }

  __syncthreads();  // all waves done READING act before overwrite

#pragma unroll
  for (int jf = 0; jf < 4; ++jf) {
    f32x4 bj = *(const f32x4*)(bias + j0 + jf * 16 + lg * 4);
#pragma unroll
    for (int rf = 0; rf < 4; ++rf) {
      f32x4 v = acc[jf][rf] + bj;
      if (MODE == 2) {
        f32x4 sm = *(const f32x4*)(seg_mean + sseg[rf] * HH + j0 + jf * 16 + lg * 4);
        v *= sm;
      }
      half4 h;
#pragma unroll
      for (int u = 0; u < 4; ++u) {
        float x = v[u];
        if (MODE == 0) x = fmaxf(x, 0.f);
        h[u] = (_Float16)x;
      }
      *(half4*)(act + swz(rf * 16 + lr, j0 + jf * 16 + lg * 4)) = h;
    }
  }
  __syncthreads();
}

// ---------------------------------------------------------------------------
// Last branch layer with FUSED OUTPUT: out = relu(W a + bias) @ ow1 + ob1.
// ---------------------------------------------------------------------------
__device__ __forceinline__ void heavy_layer_out(char* act, char* wpan,
                                                const char* __restrict__ wt3,
                                                const float* __restrict__ bias,
                                                const float* __restrict__ ow1,
                                                const float* __restrict__ ob1,
                                                float* __restrict__ out,
                                                int r0g, int tid)
{
  const int wid  = tid >> 6;
  const int lane = tid & 63;
  const int lr   = lane & 15;
  const int lg   = lane >> 4;
  const int j0   = wid << 6;
  char* slab = wpan + wid * 12288;
  const char* wsrc = wt3 + wid * 4096;

  HEAVY_MFMA_BODY(act, slab, wsrc)

  float o[4][3];
#pragma unroll
  for (int rf = 0; rf < 4; ++rf)
#pragma unroll
    for (int c = 0; c < 3; ++c) o[rf][c] = 0.f;

#pragma unroll
  for (int jf = 0; jf < 4; ++jf) {
    f32x4 bj = *(const f32x4*)(bias + j0 + jf * 16 + lg * 4);
#pragma unroll
    for (int u = 0; u < 4; ++u) {
      const int j = j0 + jf * 16 + lg * 4 + u;
      const float w0 = ow1[j * 3 + 0], w1 = ow1[j * 3 + 1], w2 = ow1[j * 3 + 2];
#pragma unroll
      for (int rf = 0; rf < 4; ++rf) {
        float x = fmaxf(acc[jf][rf][u] + bj[u], 0.f);
        o[rf][0] = fmaf(x, w0, o[rf][0]);
        o[rf][1] = fmaf(x, w1, o[rf][1]);
        o[rf][2] = fmaf(x, w2, o[rf][2]);
      }
    }
  }

#pragma unroll
  for (int rf = 0; rf < 4; ++rf)
#pragma unroll
    for (int c = 0; c < 3; ++c) {
      o[rf][c] += __shfl_xor(o[rf][c], 16);
      o[rf][c] += __shfl_xor(o[rf][c], 32);
    }

  __syncthreads();  // all waves done with their wpan slabs (ps aliases wpan)
  float* ps = (float*)wpan;  // [4 wid][64 r][3]
  if (lg == 0) {
#pragma unroll
    for (int rf = 0; rf < 4; ++rf) {
      const int r = rf * 16 + lr;
#pragma unroll
      for (int c = 0; c < 3; ++c) ps[wid * 192 + r * 3 + c] = o[rf][c];
    }
  }
  __syncthreads();
  if (tid < ROWS) {
    const int r = tid;
    float* dst = out + (size_t)(r0g + r) * 3;
#pragma unroll
    for (int c = 0; c < 3; ++c) {
      float v = ob1[c];
#pragma unroll
      for (int w = 0; w < 4; ++w) v += ps[w * 192 + r * 3 + c];
      dst[c] = v;
    }
  }
}

// layer 1 via MFMA: F=3 -> H (relu), K padded 3 -> 32 with zeros.
__device__ __forceinline__ void layer1_mfma(char* act, const float* __restrict__ x,
                                            int r0g, const float* __restrict__ W0,
                                            const float* __restrict__ b0, int tid)
{
  const int wid  = tid >> 6;
  const int lane = tid & 63;
  const int lr   = lane & 15;
  const int lg   = lane >> 4;
  const int j0   = wid << 6;

  half8 a[4];
#pragma unroll
  for (int jf = 0; jf < 4; ++jf) {
    half8 v = {0, 0, 0, 0, 0, 0, 0, 0};
    if (lg == 0) {
      int j = j0 + jf * 16 + lr;
      v[0] = (_Float16)W0[j];
      v[1] = (_Float16)W0[HH + j];
      v[2] = (_Float16)W0[2 * HH + j];
    }
    a[jf] = v;
  }

  f32x4 acc[4][4];
#pragma unroll
  for (int jf = 0; jf < 4; ++jf)
#pragma unroll
    for (int rf = 0; rf < 4; ++rf)
      acc[jf][rf] = (f32x4){0.f, 0.f, 0.f, 0.f};

#pragma unroll
  for (int rf = 0; rf < 4; ++rf) {
    half8 b = {0, 0, 0, 0, 0, 0, 0, 0};
    if (lg == 0) {
      const float* xp = x + (size_t)(r0g + rf * 16 + lr) * 3;
      b[0] = (_Float16)xp[0];
      b[1] = (_Float16)xp[1];
      b[2] = (_Float16)xp[2];
    }
#pragma unroll
    for (int jf = 0; jf < 4; ++jf)
      acc[jf][rf] = __builtin_amdgcn_mfma_f32_16x16x32_f16(a[jf], b, acc[jf][rf], 0, 0, 0);
  }

#pragma unroll
  for (int jf = 0; jf < 4; ++jf) {
    f32x4 bj = *(const f32x4*)(b0 + j0 + jf * 16 + lg * 4);
#pragma unroll
    for (int rf = 0; rf < 4; ++rf) {
      f32x4 v = acc[jf][rf] + bj;
      half4 h;
#pragma unroll
      for (int u = 0; u < 4; ++u)
        h[u] = (_Float16)fmaxf(v[u], 0.f);
      *(half4*)(act + swz(rf * 16 + lr, j0 + jf * 16 + lg * 4)) = h;
    }
  }
  __syncthreads();
}

// ---------------------------------------------------------------------------
// Trunk: only a = relu(layer2) is needed per node; tw2 applied per-segment.
// ---------------------------------------------------------------------------
__global__ __launch_bounds__(THREADS, 2)
void trunk_kernel(const float* __restrict__ nodes, const int* __restrict__ coord_seg,
                  const float* __restrict__ tw0, const float* __restrict__ tb0,
                  const char* __restrict__ wt3_1, const float* __restrict__ tb1,
                  float* __restrict__ seg_a)
{
  __shared__ __align__(16) char act[ROWS * HH * 2];   // 32KB
  __shared__ __align__(16) char wpan[4 * 12288];      // 48KB
  const int tid = threadIdx.x;
  const int r0g = blockIdx.x * ROWS;

  layer1_mfma(act, nodes, r0g, tw0, tb0, tid);
  heavy_layer<0>(act, wpan, wt3_1, tb1, nullptr, nullptr, tid);  // a

  {
    const int j = tid;
    const int s_lo = coord_seg[r0g];
    const int s_hi = coord_seg[r0g + ROWS - 1];
    if (s_lo == s_hi) {
      float p = 0.f;
#pragma unroll 8
      for (int r = 0; r < ROWS; ++r)
        p += (float)*(const _Float16*)(act + swz(r, j));
      atomicAdd(&seg_a[s_lo * HH + j], p);
    } else {
      for (int s = s_lo; s <= s_hi; ++s) {
        float p = 0.f;
        for (int r = 0; r < ROWS; ++r)
          if (coord_seg[r0g + r] == s)
            p += (float)*(const _Float16*)(act + swz(r, j));
        atomicAdd(&seg_a[s * HH + j], p);
      }
    }
  }
}

// ---------------------------------------------------------------------------
// cfuse+segprep merged: block (s, kc) computes seg_mean[s] locally in LDS
// (~1us redundant VALU vs a separate launch + global round-trip), then
// C_s[j][k] = sum_i bw2[k][i]*m_s[i]*ow0[i][j] in WT3 slab layout.
// kc==0 blocks also publish seg_mean and d_s for branch's mixed path.
// ---------------------------------------------------------------------------
__global__ __launch_bounds__(THREADS, 2)
void cfuse_kernel(const float* __restrict__ seg_a, const int* __restrict__ coord_seg,
                  const float* __restrict__ tw2, const float* __restrict__ tb2,
                  const float* __restrict__ bw2, const float* __restrict__ bb2,
                  const float* __restrict__ ow0, const float* __restrict__ ob0,
                  const char* __restrict__ wt3_ow0,
                  float* __restrict__ seg_mean_g, float* __restrict__ d_s,
                  char* __restrict__ Cbuf)
{
  __shared__ __align__(16) char act[ROWS * HH * 2];
  __shared__ __align__(16) char wpan[4 * 12288];
  __shared__ float sm[HH];
  const int tid = threadIdx.x;
  const int s  = blockIdx.x >> 2;
  const int kc = blockIdx.x & 3;
  const int k0 = kc * 64;

  // segprep (local): seg_mean[s][j] via binary search + 256-FMA dot
  {
    const int j = tid;
    int lo = 0, n = NTOT;
    while (n > 0) { int h = n >> 1; int mid = lo + h;
      if (coord_seg[mid] < s) { lo = mid + 1; n -= h + 1; } else n = h; }
    int hi = lo; n = NTOT - lo;
    while (n > 0) { int h = n >> 1; int mid = hi + h;
      if (coord_seg[mid] < s + 1) { hi = mid + 1; n -= h + 1; } else n = h; }
    const float cnt = (float)(hi - lo);
    float acc0 = cnt * tb2[j];
    for (int i = 0; i < HH; ++i)
      acc0 = fmaf(seg_a[s * HH + i], tw2[i * HH + j], acc0);
    acc0 /= fmaxf(cnt, 1.0f);
    sm[j] = acc0;
    if (kc == 0) seg_mean_g[s * HH + j] = acc0;
  }
  __syncthreads();
  if (kc == 0) {
    const int j = tid;
    float d = ob0[j];
    for (int i = 0; i < HH; ++i)
      d = fmaf(bb2[i] * sm[i], ow0[i * HH + j], d);
    d_s[s * HH + j] = d;
  }

  // act[r'][i] = fp16(bw2[k0+r'][i] * m_s[i])
  {
    const int i = tid;
    const float mi = sm[i];
    for (int r = 0; r < ROWS; ++r)
      *(_Float16*)(act + swz(r, i)) = (_Float16)(bw2[(size_t)(k0 + r) * HH + i] * mi);
  }
  __syncthreads();

  const int wid  = tid >> 6;
  const int lane = tid & 63;
  const int lr   = lane & 15;
  const int lg   = lane >> 4;
  const int j0   = wid << 6;
  char* slab = wpan + wid * 12288;
  const char* wsrc = wt3_ow0 + wid * 4096;

  HEAVY_MFMA_BODY(act, slab, wsrc)

  // dbuf[j][k'] fp16, row 128B, byte = j*128 + (k'*2 ^ ((j&7)<<4))
  __syncthreads();
  char* dbuf = wpan;
#pragma unroll
  for (int jf = 0; jf < 4; ++jf)
#pragma unroll
    for (int rf = 0; rf < 4; ++rf) {
      const int kl = rf * 16 + lr;
#pragma unroll
      for (int u = 0; u < 4; ++u) {
        const int j = j0 + jf * 16 + lg * 4 + u;
        *(_Float16*)(dbuf + j * 128 + ((kl * 2) ^ ((j & 7) << 4))) = (_Float16)acc[jf][rf][u];
      }
    }
  __syncthreads();

  char* Cdst = Cbuf + (size_t)s * 131072 + (size_t)(kc * 2) * 16384;
#pragma unroll
  for (int c = 0; c < 8; ++c) {
    const uint32_t g = c * 4096 + tid * 16;
    const uint32_t sl = g >> 14;
    const uint32_t aa = g & 16383;
    const uint32_t wq = aa >> 12;
    const uint32_t jjf = (aa >> 10) & 3;
    const uint32_t l  = (aa >> 4) & 63;
    const uint32_t j  = wq * 64 + jjf * 16 + (l & 15);
    const uint32_t kl = sl * 32 + ((l >> 4) << 3);
    uint4 v = *(const uint4*)(dbuf + j * 128 + ((kl * 2) ^ ((j & 7) << 4)));
    *(uint4*)(Cdst + sl * 16384 + aa) = v;
  }
}

__global__ __launch_bounds__(THREADS, 2)
void branch_kernel(const float* __restrict__ known_nodes, const int* __restrict__ known_seg,
                   const float* __restrict__ bw0, const float* __restrict__ bb0,
                   const char* __restrict__ wt3_1, const float* __restrict__ bb1,
                   const char* __restrict__ wt3_2, const float* __restrict__ bb2,
                   const float* __restrict__ seg_mean,
                   const char* __restrict__ wt3_o, const float* __restrict__ ob0,
                   const float* __restrict__ ow1, const float* __restrict__ ob1,
                   const char* __restrict__ Cbuf, const float* __restrict__ d_s,
                   int use_fuse, float* __restrict__ out)
{
  __shared__ __align__(16) char act[ROWS * HH * 2];
  __shared__ __align__(16) char wpan[4 * 12288];
  const int tid = threadIdx.x;
  // XCD-aware bijective swizzle: same-segment blocks share an XCD.
  const int bid = ((int)blockIdx.x & 7) * ((int)gridDim.x >> 3) + ((int)blockIdx.x >> 3);
  const int r0g = bid * ROWS;

  layer1_mfma(act, known_nodes, r0g, bw0, bb0, tid);
  heavy_layer<0>(act, wpan, wt3_1, bb1, nullptr, nullptr, tid);

  const int s_lo = known_seg[r0g];
  const int s_hi = known_seg[r0g + ROWS - 1];
  if (use_fuse && s_lo == s_hi) {
    heavy_layer_out(act, wpan, Cbuf + (size_t)s_lo * 131072, d_s + s_lo * HH,
                    ow1, ob1, out, r0g, tid);
  } else {
    heavy_layer<2>(act, wpan, wt3_2, bb2, seg_mean, known_seg + r0g, tid);
    heavy_layer_out(act, wpan, wt3_o, ob0, ow1, ob1, out, r0g, tid);
  }
}

// W fp32 (row=k,col=j) -> WT3 slab-linear fp16 (4 matrices) + seg_a zeroing.
struct WPtrs { const float* w[4]; char* wt3[4]; };
__global__ void transpose_kernel(WPtrs p, float* __restrict__ seg_a)
{
  const int m = blockIdx.x >> 8;
  const int k = blockIdx.x & 255;
  const int j = threadIdx.x;
  if (blockIdx.x < 16) {
    float4 z = {0.f, 0.f, 0.f, 0.f};
    *(float4*)(seg_a + (size_t)blockIdx.x * 1024 + j * 4) = z;
  }
  size_t off = (size_t)(k >> 5) * 16384 + (size_t)(j >> 6) * 4096
             + (size_t)((j >> 4) & 3) * 1024
             + (size_t)((((k >> 3) & 3) << 4) | (j & 15)) * 16
             + (size_t)(k & 7) * 2;
  *(_Float16*)(p.wt3[m] + off) = (_Float16)p.w[m][k * HH + j];
}

// ---------------------------------------------------------------------------
extern "C" void kernel_launch(void* const* d_in, const int* in_sizes, int n_in,
                              void* d_out, int out_size, void* d_ws, size_t ws_size,
                              hipStream_t stream)
{
  const float* known_nodes = (const float*)d_in[0];
  const float* nodes       = (const float*)d_in[1];
  const int*   known_seg   = (const int*)d_in[2];
  const int*   coord_seg   = (const int*)d_in[3];
  const float* bw0 = (const float*)d_in[4];
  const float* bb0 = (const float*)d_in[5];
  const float* bw1 = (const float*)d_in[6];
  const float* bb1 = (const float*)d_in[7];
  const float* bw2 = (const float*)d_in[8];
  const float* bb2 = (const float*)d_in[9];
  const float* tw0 = (const float*)d_in[10];
  const float* tb0 = (const float*)d_in[11];
  const float* tw1 = (const float*)d_in[12];
  const float* tb1 = (const float*)d_in[13];
  const float* tw2 = (const float*)d_in[14];
  const float* tb2 = (const float*)d_in[15];
  const float* ow0 = (const float*)d_in[16];
  const float* ob0 = (const float*)d_in[17];
  const float* ow1 = (const float*)d_in[18];
  const float* ob1 = (const float*)d_in[19];

  float* out      = (float*)d_out;
  char* p = (char*)d_ws;
  float* seg_a    = (float*)p;            p += (size_t)NB * HH * 4;
  float* seg_mean = (float*)p;            p += (size_t)NB * HH * 4;
  char* wt3_tw1 = p;  p += (size_t)HH * HH * 2;
  char* wt3_bw1 = p;  p += (size_t)HH * HH * 2;
  char* wt3_bw2 = p;  p += (size_t)HH * HH * 2;
  char* wt3_ow0 = p;  p += (size_t)HH * HH * 2;
  float* d_s    = (float*)p;              p += (size_t)NB * HH * 4;
  char* Cbuf    = p;                      p += (size_t)NB * HH * HH * 2;  // 8MB
  const int use_fuse = ((size_t)(p - (char*)d_ws) <= ws_size) ? 1 : 0;

  WPtrs wp;
  wp.w[0] = tw1; wp.wt3[0] = wt3_tw1;
  wp.w[1] = bw1; wp.wt3[1] = wt3_bw1;
  wp.w[2] = bw2; wp.wt3[2] = wt3_bw2;
  wp.w[3] = ow0; wp.wt3[3] = wt3_ow0;

  transpose_kernel<<<4 * 256, 256, 0, stream>>>(wp, seg_a);
  trunk_kernel<<<NTOT / ROWS, THREADS, 0, stream>>>(nodes, coord_seg,
                                                    tw0, tb0, wt3_tw1, tb1,
                                                    seg_a);
  if (use_fuse) {
    cfuse_kernel<<<NB * 4, THREADS, 0, stream>>>(seg_a, coord_seg, tw2, tb2,
                                                 bw2, bb2, ow0, ob0, wt3_ow0,
                                                 seg_mean, d_s, Cbuf);
  }
  branch_kernel<<<NTOT / ROWS, THREADS, 0, stream>>>(known_nodes, known_seg,
                                                     bw0, bb0, wt3_bw1, bb1, wt3_bw2, bb2,
                                                     seg_mean,
                                                     wt3_ow0, ob0, ow1, ob1,
                                                     Cbuf, d_s, use_fuse,
                                                     out);
}